// Round 4
// baseline (1046.648 us; speedup 1.0000x reference)
//
#include <hip/hip_runtime.h>
#include <math.h>

#define NTHR 512
#define NB 2              // batches per WG (kernel1)
#define NROWSR (NB * 20)  // 40 real rows

using bf8 = __attribute__((ext_vector_type(8))) short;
using f4  = __attribute__((ext_vector_type(4))) float;

// kernel1 LDS pool (bytes). Planar hi/lo bf16: [plane][40][PK], 4B/elem total.
#define H1_OFF 0
#define H1_PK 162        // 40*162*4 = 25920
#define H2_OFF 25920
#define H2_PK 132        // 40*132*4 = 21120 -> end 47040
#define FEAT_OFF 0       // aliases H1 (dead after P2)
#define FEAT_PK 132
#define S1_OFF 25920     // aliases H2 (dead after P3)
#define S1_PK 132
#define POOL1 47040

// ws fragment bases (1KB blocks; each (kb,nt) = 2 blocks hi+lo)
#define L1B 0
#define L2B 20
#define L3B 90
#define A1B 146
#define A2B 202
#define M1B 258
#define M2B 338
#define M3B 408
#define JOINT_F 118784   // float offset of joint[16384][106] in ws

// kernel2
#define K2ROWS 64
#define K2THR 256
#define K2_JT_OFF 0      // 64*136*4 = 34816
#define K2_V1_OFF 34816  // 64*168*4 = 43008 -> end 77824
#define K2_POOL 77824

__device__ __forceinline__ float relu_f(float v) { return fmaxf(v, 0.f); }
__device__ __forceinline__ float us2f(ushort u) {
  return __builtin_bit_cast(float, (uint)u << 16);
}
__device__ __forceinline__ void split_store(float v, ushort* p, int pstride) {
  uint bits = __builtin_bit_cast(uint, v);
  float hf = __builtin_bit_cast(float, bits & 0xffff0000u);
  float lf = v - hf;
  p[0] = (ushort)(bits >> 16);
  p[pstride] = (ushort)(__builtin_bit_cast(uint, lf) >> 16);
}

// ---------------- prep: pack hi/lo bf16 B-fragments ----------------
__global__ __launch_bounds__(64) void prep_kernel(
    const float* __restrict__ w1, const float* __restrict__ w2,
    const float* __restrict__ w3, const float* __restrict__ a1,
    const float* __restrict__ a2, const float* __restrict__ m1,
    const float* __restrict__ m2, const float* __restrict__ m3,
    uint4* __restrict__ ws) {
  const int job = blockIdx.x;
  const int lane = threadIdx.x;
  const float* W;
  int K, C, NT, base, kb, nt, i;
  if (job < 10)       { W = w1; K = 13;  C = 150; NT = 10; base = L1B; kb = 0; nt = job; }
  else if (job < 45)  { W = w2; K = 150; C = 100; NT = 7;  base = L2B; i = job - 10;  kb = i / 7;  nt = i % 7; }
  else if (job < 73)  { W = w3; K = 100; C = 100; NT = 7;  base = L3B; i = job - 45;  kb = i / 7;  nt = i % 7; }
  else if (job < 101) { W = a1; K = 100; C = 100; NT = 7;  base = A1B; i = job - 73;  kb = i / 7;  nt = i % 7; }
  else if (job < 129) { W = a2; K = 100; C = 100; NT = 7;  base = A2B; i = job - 101; kb = i / 7;  nt = i % 7; }
  else if (job < 169) { W = m1; K = 106; C = 150; NT = 10; base = M1B; i = job - 129; kb = i / 10; nt = i % 10; }
  else if (job < 204) { W = m2; K = 150; C = 100; NT = 7;  base = M2B; i = job - 169; kb = i / 7;  nt = i % 7; }
  else                { W = m3; K = 100; C = 100; NT = 7;  base = M3B; i = job - 204; kb = i / 7;  nt = i % 7; }
  const int r = lane & 15, g = lane >> 4;
  const int j = nt * 16 + r;
  uint hi[8], lo[8];
  for (int e = 0; e < 8; ++e) {
    int k = kb * 32 + g * 8 + e;
    float v = (k < K && j < C) ? W[k * C + j] : 0.f;
    uint bits = __builtin_bit_cast(uint, v);
    hi[e] = bits >> 16;
    float hf = __builtin_bit_cast(float, bits & 0xffff0000u);
    float lf = v - hf;
    lo[e] = __builtin_bit_cast(uint, lf) >> 16;
  }
  uint4 vh = { hi[0] | (hi[1] << 16), hi[2] | (hi[3] << 16),
               hi[4] | (hi[5] << 16), hi[6] | (hi[7] << 16) };
  uint4 vl = { lo[0] | (lo[1] << 16), lo[2] | (lo[3] << 16),
               lo[4] | (lo[5] << 16), lo[6] | (lo[7] << 16) };
  ws[(size_t)(base + (kb * NT + nt) * 2 + 0) * 64 + lane] = vh;
  ws[(size_t)(base + (kb * NT + nt) * 2 + 1) * 64 + lane] = vl;
}

// ---------------- generic MFMA dense layer ----------------
// MODE: 0 relu->planar, 1 linear->planar + gs-atomic,
//       2 relu+gpart->planar, 3 relu -> score shfl-reduce + sce atomic (no store)
template <int KB, int NT, int C, int MODE, int MTL, int ROWS, int RVALID, bool W8>
__device__ __forceinline__ void mfma_layer(
    char* pool, int inOff, int PKin, int outOff, int PKout,
    const bf8* __restrict__ wsB, const float* __restrict__ bias,
    const float* gpartL, float* gsL, float* sceL, const float* __restrict__ a3,
    int lane, int wid) {
  constexpr int NTP = (NT + 1) / 2;
  const int r = lane & 15, g = lane >> 4;
  const char* Ain = pool + inOff;
  const int pstrIn = ROWS * PKin * 2;
  int wlo, mtb, mte;
  if constexpr (W8) {
    wlo = wid & 3;
    const int whi = wid >> 2;
    mtb = whi ? 2 : 0; mte = whi ? MTL : 2;
  } else { wlo = wid; mtb = 0; mte = MTL; }
  for (int p = wlo; p < NTP; p += 4) {
    const int nt0 = 2 * p;
    const bool two = (nt0 + 1 < NT);
    bf8 bh0[KB], bl0[KB], bh1[KB], bl1[KB];
#pragma unroll
    for (int kb = 0; kb < KB; ++kb) {
      bh0[kb] = wsB[((kb * NT + nt0) * 2 + 0) * 64 + lane];
      bl0[kb] = wsB[((kb * NT + nt0) * 2 + 1) * 64 + lane];
      if (two) {
        bh1[kb] = wsB[((kb * NT + nt0 + 1) * 2 + 0) * 64 + lane];
        bl1[kb] = wsB[((kb * NT + nt0 + 1) * 2 + 1) * 64 + lane];
      }
    }
    for (int mt = mtb; mt < mte; ++mt) {
      int rA = mt * 16 + r;
      if constexpr (MTL * 16 > ROWS) { if (rA >= ROWS) rA = mt * 16 + (r & 7); }
      f4 acc0 = {0.f, 0.f, 0.f, 0.f}, acc1 = {0.f, 0.f, 0.f, 0.f};
      const char* aHi = Ain + rA * (PKin * 2) + g * 16;
      const char* aLo = aHi + pstrIn;
#pragma unroll
      for (int kb = 0; kb < KB; ++kb) {
        bf8 ah = *(const bf8*)(aHi + kb * 64);
        bf8 al = *(const bf8*)(aLo + kb * 64);
        acc0 = __builtin_amdgcn_mfma_f32_16x16x32_bf16(ah, bh0[kb], acc0, 0, 0, 0);
        if (two) acc1 = __builtin_amdgcn_mfma_f32_16x16x32_bf16(ah, bh1[kb], acc1, 0, 0, 0);
        acc0 = __builtin_amdgcn_mfma_f32_16x16x32_bf16(al, bh0[kb], acc0, 0, 0, 0);
        if (two) acc1 = __builtin_amdgcn_mfma_f32_16x16x32_bf16(al, bh1[kb], acc1, 0, 0, 0);
        acc0 = __builtin_amdgcn_mfma_f32_16x16x32_bf16(ah, bl0[kb], acc0, 0, 0, 0);
        if (two) acc1 = __builtin_amdgcn_mfma_f32_16x16x32_bf16(ah, bl1[kb], acc1, 0, 0, 0);
      }
#pragma unroll
      for (int t = 0; t < 2; ++t) {
        if (t && !two) break;
        const int nt = nt0 + t;
        const f4 acc = t ? acc1 : acc0;
        const int col = nt * 16 + r;
        const int rbase = mt * 16 + g * 4;
        const float bcol = (col < C) ? bias[col] : 0.f;
        float gp = 0.f;
        if constexpr (MODE == 2) {
          const int rb = rbase / 20;
          if (rb < NB && col < C) gp = gpartL[rb * 100 + col];
        }
        float a3c = 0.f;
        if constexpr (MODE == 3) { if (col < C) a3c = a3[col]; }
        float vsum = 0.f;
#pragma unroll
        for (int q = 0; q < 4; ++q) {
          const int orow = rbase + q;
          float v = 0.f;
          if (orow < RVALID && col < C) {
            v = acc[q] + bcol;
            if constexpr (MODE == 2) v += gp;
            if constexpr (MODE != 1) v = fmaxf(v, 0.f);
          }
          if constexpr (MODE == 3) {
            float val = v * a3c;
            val += __shfl_xor(val, 1);
            val += __shfl_xor(val, 2);
            val += __shfl_xor(val, 4);
            val += __shfl_xor(val, 8);
            if (r == 0 && orow < RVALID) atomicAdd(&sceL[orow], val);
          } else {
            vsum += v;
            if (orow < RVALID) {
              ushort* oHi = (ushort*)(pool + outOff) + orow * PKout + col;
              split_store(v, oHi, ROWS * PKout);
            }
          }
        }
        if constexpr (MODE == 1) {
          if (col < C && rbase < RVALID)
            atomicAdd(&gsL[(rbase / 20) * 100 + col], vsum);
        }
      }
    }
  }
}

// zero cols [112,128) of a planar buffer (epilogue covers [C,112) with 0s)
template <int ROWSZ, int PK>
__device__ __forceinline__ void zero_tail(char* pool, int off, int tid) {
  if (tid < 2 * ROWSZ) {
    int row = tid >> 1, pl = tid & 1;
    uint2* z = (uint2*)((ushort*)(pool + off) + (size_t)pl * ROWSZ * PK + row * PK + 112);
#pragma unroll
    for (int u = 0; u < 4; ++u) z[u] = uint2{0, 0};
  }
}

// ---------------- L1: A-fragments built in registers from state ----------------
__device__ __forceinline__ void l1_layer(
    const float* __restrict__ state, int b0, char* pool,
    const bf8* __restrict__ wsB, const float* __restrict__ bias,
    int lane, int wid) {
  const int r = lane & 15, g = lane >> 4;
  const int wlo = wid & 3, whi = wid >> 2;
  const int mtb = whi ? 2 : 0, mte = whi ? 3 : 2;
  for (int mt = mtb; mt < mte; ++mt) {
    const int rl = mt * 16 + r;
    bf8 ah = __builtin_bit_cast(bf8, (uint4){0, 0, 0, 0});
    bf8 al = ah;
    if (rl < NROWSR) {
      const float* sp = state + ((size_t)b0 * 20 + rl) * 13;
      uint hv[8], lv[8];
#pragma unroll
      for (int e = 0; e < 8; ++e) {
        int k = g * 8 + e;
        float v = (k < 13) ? sp[k] : 0.f;
        uint bits = __builtin_bit_cast(uint, v);
        hv[e] = bits >> 16;
        float hf = __builtin_bit_cast(float, bits & 0xffff0000u);
        lv[e] = __builtin_bit_cast(uint, v - hf) >> 16;
      }
      uint4 H = {hv[0] | (hv[1] << 16), hv[2] | (hv[3] << 16),
                 hv[4] | (hv[5] << 16), hv[6] | (hv[7] << 16)};
      uint4 L = {lv[0] | (lv[1] << 16), lv[2] | (lv[3] << 16),
                 lv[4] | (lv[5] << 16), lv[6] | (lv[7] << 16)};
      ah = __builtin_bit_cast(bf8, H);
      al = __builtin_bit_cast(bf8, L);
    }
    for (int p = wlo; p < 5; p += 4) {
      const int nt0 = 2 * p;
      bf8 bh0 = wsB[((nt0) * 2 + 0) * 64 + lane];
      bf8 bl0 = wsB[((nt0) * 2 + 1) * 64 + lane];
      bf8 bh1 = wsB[((nt0 + 1) * 2 + 0) * 64 + lane];
      bf8 bl1 = wsB[((nt0 + 1) * 2 + 1) * 64 + lane];
      f4 acc0 = {0.f, 0.f, 0.f, 0.f}, acc1 = {0.f, 0.f, 0.f, 0.f};
      acc0 = __builtin_amdgcn_mfma_f32_16x16x32_bf16(ah, bh0, acc0, 0, 0, 0);
      acc1 = __builtin_amdgcn_mfma_f32_16x16x32_bf16(ah, bh1, acc1, 0, 0, 0);
      acc0 = __builtin_amdgcn_mfma_f32_16x16x32_bf16(al, bh0, acc0, 0, 0, 0);
      acc1 = __builtin_amdgcn_mfma_f32_16x16x32_bf16(al, bh1, acc1, 0, 0, 0);
      acc0 = __builtin_amdgcn_mfma_f32_16x16x32_bf16(ah, bl0, acc0, 0, 0, 0);
      acc1 = __builtin_amdgcn_mfma_f32_16x16x32_bf16(ah, bl1, acc1, 0, 0, 0);
#pragma unroll
      for (int t = 0; t < 2; ++t) {
        const int nt = nt0 + t;
        const f4 acc = t ? acc1 : acc0;
        const int col = nt * 16 + r;
        const int rbase = mt * 16 + g * 4;
        const float bcol = (col < 150) ? bias[col] : 0.f;
#pragma unroll
        for (int q = 0; q < 4; ++q) {
          const int orow = rbase + q;
          if (orow < NROWSR) {
            float v = (col < 150) ? fmaxf(acc[q] + bcol, 0.f) : 0.f;
            ushort* oHi = (ushort*)(pool + H1_OFF) + orow * H1_PK + col;
            split_store(v, oHi, 40 * H1_PK);
          }
        }
      }
    }
  }
}

// ---------------- kernel1: MLP1 + attention -> joint ----------------
__global__ __launch_bounds__(NTHR, 6) void value_net_kernel(
    const float* __restrict__ state,
    const float* __restrict__ b1, const float* __restrict__ b2,
    const float* __restrict__ b3,
    const float* __restrict__ a1, const float* __restrict__ ab1,
    const float* __restrict__ ab2,
    const float* __restrict__ a3, const float* __restrict__ ab3,
    const uint4* __restrict__ ws, float* __restrict__ jointg) {
  __shared__ char pool[POOL1];
  __shared__ float gsL[200], gpartL[200], sceL[40], swL[40];

  const int tid = threadIdx.x;
  const int lane = tid & 63, wid = tid >> 6;
  const int b0 = blockIdx.x * NB;
  const bf8* wsb = (const bf8*)ws;

  // P1: L1 13->150 relu (A from state via regs) -> H1
  l1_layer(state, b0, pool, wsb + L1B * 64, b1, lane, wid);
  __syncthreads();

  // P2: zero gsL; zero H2 tail; L2 150->100 relu H1->H2
  if (tid < 200) gsL[tid] = 0.f;
  zero_tail<40, H2_PK>(pool, H2_OFF, tid);
  mfma_layer<5, 7, 100, 0, 3, 40, NROWSR, true>(
      pool, H1_OFF, H1_PK, H2_OFF, H2_PK, wsb + L2B * 64, b2,
      nullptr, nullptr, nullptr, nullptr, lane, wid);
  __syncthreads();

  // P3: zero FEAT tail; L3 100->100 linear H2->FEAT (+ gs atomics)
  zero_tail<40, FEAT_PK>(pool, FEAT_OFF, tid);
  mfma_layer<4, 7, 100, 1, 3, 40, NROWSR, true>(
      pool, H2_OFF, H2_PK, FEAT_OFF, FEAT_PK, wsb + L3B * 64, b3,
      nullptr, gsL, nullptr, nullptr, lane, wid);
  __syncthreads();

  // P4: gpart = (gs*0.05) @ a1[100:200]; zero sceL
  if (tid < 400) {
    const int b = tid / 200, rem = tid - b * 200;
    const int j = rem >> 1, half = rem & 1;
    float acc = 0.f;
    const float* gsb = gsL + b * 100;
    for (int k = half * 50; k < half * 50 + 50; ++k)
      acc += gsb[k] * a1[(100 + k) * 100 + j];
    acc += __shfl_xor(acc, 1);
    if (half == 0) gpartL[b * 100 + j] = acc * 0.05f;
  } else if (tid < 440) {
    sceL[tid - 400] = 0.f;
  }
  __syncthreads();

  // P5: zero S1 tail; A1 (feat half) + gpart, relu -> S1
  zero_tail<40, S1_PK>(pool, S1_OFF, tid);
  mfma_layer<4, 7, 100, 2, 3, 40, NROWSR, true>(
      pool, FEAT_OFF, FEAT_PK, S1_OFF, S1_PK, wsb + A1B * 64, ab1,
      gpartL, nullptr, nullptr, nullptr, lane, wid);
  __syncthreads();

  // P6: A2 relu + fold A3 dot -> sceL atomics (no planar out)
  mfma_layer<4, 7, 100, 3, 3, 40, NROWSR, true>(
      pool, S1_OFF, S1_PK, 0, 0, wsb + A2B * 64, ab2,
      nullptr, nullptr, sceL, a3, lane, wid);
  __syncthreads();

  // P7: softmax over n (relu(score+ab3))
  if (tid < NROWSR) {
    const int b = tid / 20, n = tid - b * 20;
    const float ab3v = ab3[0];
    float m = -1e30f;
    for (int i = 0; i < 20; ++i) m = fmaxf(m, relu_f(sceL[b * 20 + i] + ab3v));
    float sum = 0.f, mine = 0.f;
    for (int i = 0; i < 20; ++i) {
      float e = __expf(relu_f(sceL[b * 20 + i] + ab3v) - m);
      sum += e;
      if (i == n) mine = e;
    }
    swL[tid] = mine / sum;
  }
  __syncthreads();

  // P8: weighted feature + self -> jointg
  if (tid < 400) {
    const int b = tid / 200, rem = tid - b * 200;
    const int d = rem >> 1, half = rem & 1;
    const ushort* fh = (const ushort*)(pool + FEAT_OFF);
    const ushort* fl = fh + 40 * FEAT_PK;
    float acc = 0.f;
    for (int n = half * 10; n < half * 10 + 10; ++n) {
      const int rw = b * 20 + n;
      acc += swL[b * 20 + n] * (us2f(fh[rw * FEAT_PK + d]) + us2f(fl[rw * FEAT_PK + d]));
    }
    acc += __shfl_xor(acc, 1);
    if (half == 0) jointg[(size_t)(b0 + b) * 106 + 6 + d] = acc;
  } else if (tid < 412) {
    const int idx = tid - 400, b = idx / 6, i = idx - b * 6;
    jointg[(size_t)(b0 + b) * 106 + i] = state[(b0 + b) * 260 + i];
  }
}

// ---------------- kernel2: M-MLP GEMM over 16384 rows ----------------
__global__ __launch_bounds__(K2THR) void mlp2_kernel(
    const float* __restrict__ jointg,
    const float* __restrict__ mb1, const float* __restrict__ mb2,
    const float* __restrict__ mb3,
    const float* __restrict__ m4, const float* __restrict__ mb4,
    const uint4* __restrict__ ws, float* __restrict__ out) {
  __shared__ char pool[K2_POOL];
  __shared__ float m4L[100];
  const int tid = threadIdx.x, lane = tid & 63, wid = tid >> 6;
  const size_t r0 = (size_t)blockIdx.x * K2ROWS;
  const bf8* wsb = (const bf8*)ws;

  // stage joint -> planar hi/lo (PK=136, cols 106..135 zero); m4 -> LDS
  for (int i = tid; i < K2ROWS * 136; i += K2THR) {
    int row = i / 136, k = i - row * 136;
    float v = (k < 106) ? jointg[(r0 + row) * 106 + k] : 0.f;
    split_store(v, (ushort*)(pool + K2_JT_OFF) + row * 136 + k, K2ROWS * 136);
  }
  if (tid < 100) m4L[tid] = m4[tid];
  __syncthreads();

  // M1: 106->150 relu (joint PK136 -> v1 PK168)
  mfma_layer<4, 10, 150, 0, 4, K2ROWS, K2ROWS, false>(
      pool, K2_JT_OFF, 136, K2_V1_OFF, 168, wsb + M1B * 64, mb1,
      nullptr, nullptr, nullptr, nullptr, lane, wid);
  __syncthreads();

  // M2: 150->100 relu (v1 -> v2 @0, PK136)
  zero_tail<K2ROWS, 136>(pool, 0, tid);
  mfma_layer<5, 7, 100, 0, 4, K2ROWS, K2ROWS, false>(
      pool, K2_V1_OFF, 168, 0, 136, wsb + M2B * 64, mb2,
      nullptr, nullptr, nullptr, nullptr, lane, wid);
  __syncthreads();

  // M3: 100->100 relu (v2 -> v3 @V1_OFF, PK136)
  mfma_layer<4, 7, 100, 0, 4, K2ROWS, K2ROWS, false>(
      pool, 0, 136, K2_V1_OFF, 136, wsb + M3B * 64, mb3,
      nullptr, nullptr, nullptr, nullptr, lane, wid);
  __syncthreads();

  // M4: 100->1
  {
    const int row = tid >> 2, seg = tid & 3;
    const ushort* vh = (const ushort*)(pool + K2_V1_OFF);
    const ushort* vl = vh + K2ROWS * 136;
    float s = 0.f;
    for (int k = seg; k < 100; k += 4)
      s += (us2f(vh[row * 136 + k]) + us2f(vl[row * 136 + k])) * m4L[k];
    s += __shfl_xor(s, 1);
    s += __shfl_xor(s, 2);
    if (seg == 0) out[r0 + row] = s + mb4[0];
  }
}

extern "C" void kernel_launch(void* const* d_in, const int* in_sizes, int n_in,
                              void* d_out, int out_size, void* d_ws, size_t ws_size,
                              hipStream_t stream) {
  const float* state = (const float*)d_in[0];
  const float* w1 = (const float*)d_in[1];
  const float* b1 = (const float*)d_in[2];
  const float* w2 = (const float*)d_in[3];
  const float* b2 = (const float*)d_in[4];
  const float* w3 = (const float*)d_in[5];
  const float* b3 = (const float*)d_in[6];
  const float* a1 = (const float*)d_in[7];
  const float* ab1 = (const float*)d_in[8];
  const float* a2 = (const float*)d_in[9];
  const float* ab2 = (const float*)d_in[10];
  const float* a3 = (const float*)d_in[11];
  const float* ab3 = (const float*)d_in[12];
  const float* m1 = (const float*)d_in[13];
  const float* mb1 = (const float*)d_in[14];
  const float* m2 = (const float*)d_in[15];
  const float* mb2 = (const float*)d_in[16];
  const float* m3 = (const float*)d_in[17];
  const float* mb3 = (const float*)d_in[18];
  const float* m4 = (const float*)d_in[19];
  const float* mb4 = (const float*)d_in[20];
  float* out = (float*)d_out;
  uint4* ws = (uint4*)d_ws;
  float* jointg = (float*)d_ws + JOINT_F;

  prep_kernel<<<232, 64, 0, stream>>>(w1, w2, w3, a1, a2, m1, m2, m3, ws);

  const int B = in_sizes[0] / 260;  // 16384
  value_net_kernel<<<dim3(B / NB), dim3(NTHR), 0, stream>>>(
      state, b1, b2, b3, a1, ab1, ab2, a3, ab3, (const uint4*)ws, jointg);

  mlp2_kernel<<<dim3(B / K2ROWS), dim3(K2THR), 0, stream>>>(
      jointg, mb1, mb2, mb3, m4, mb4, (const uint4*)ws, out);
}

// Round 5
// 816.370 us; speedup vs baseline: 1.2821x; 1.2821x over previous
//
#include <hip/hip_runtime.h>
#include <math.h>

#define NTHR 512
#define NB 2              // batches per WG (kernel1)
#define NROWSR (NB * 20)  // 40 real rows

using bf8 = __attribute__((ext_vector_type(8))) short;
using f4  = __attribute__((ext_vector_type(4))) float;

// kernel1 LDS pool (bytes). Planar hi/lo bf16: [plane][40][PK], 4B/elem total.
#define H1_OFF 0
#define H1_PK 162        // 40*162*4 = 25920
#define H2_OFF 25920
#define H2_PK 132        // 40*132*4 = 21120 -> end 47040
#define FEAT_OFF 0       // aliases H1 (dead after P2)
#define FEAT_PK 132
#define S1_OFF 25920     // aliases H2 (dead after P3)
#define S1_PK 132
#define POOL1 47040

// ws fragment bases (1KB blocks; each (kb,nt) = 2 blocks hi+lo)
#define L1B 0
#define L2B 20
#define L3B 90
#define A1B 146
#define A2B 202
#define M1B 258
#define M2B 338
#define M3B 408
#define JOINT_F 118784   // float offset of joint[16384][106] in ws

// kernel2
#define K2ROWS 64
#define K2THR 256
#define K2_JT_OFF 0      // 64*136*4 = 34816
#define K2_V1_OFF 34816  // 64*168*4 = 43008 -> end 77824
#define K2_POOL 77824

__device__ __forceinline__ float relu_f(float v) { return fmaxf(v, 0.f); }
__device__ __forceinline__ float us2f(ushort u) {
  return __builtin_bit_cast(float, (uint)u << 16);
}
__device__ __forceinline__ void split_store(float v, ushort* p, int pstride) {
  uint bits = __builtin_bit_cast(uint, v);
  float hf = __builtin_bit_cast(float, bits & 0xffff0000u);
  float lf = v - hf;
  p[0] = (ushort)(bits >> 16);
  p[pstride] = (ushort)(__builtin_bit_cast(uint, lf) >> 16);
}

// ---------------- prep: pack hi/lo bf16 B-fragments ----------------
__global__ __launch_bounds__(64) void prep_kernel(
    const float* __restrict__ w1, const float* __restrict__ w2,
    const float* __restrict__ w3, const float* __restrict__ a1,
    const float* __restrict__ a2, const float* __restrict__ m1,
    const float* __restrict__ m2, const float* __restrict__ m3,
    uint4* __restrict__ ws) {
  const int job = blockIdx.x;
  const int lane = threadIdx.x;
  const float* W;
  int K, C, NT, base, kb, nt, i;
  if (job < 10)       { W = w1; K = 13;  C = 150; NT = 10; base = L1B; kb = 0; nt = job; }
  else if (job < 45)  { W = w2; K = 150; C = 100; NT = 7;  base = L2B; i = job - 10;  kb = i / 7;  nt = i % 7; }
  else if (job < 73)  { W = w3; K = 100; C = 100; NT = 7;  base = L3B; i = job - 45;  kb = i / 7;  nt = i % 7; }
  else if (job < 101) { W = a1; K = 100; C = 100; NT = 7;  base = A1B; i = job - 73;  kb = i / 7;  nt = i % 7; }
  else if (job < 129) { W = a2; K = 100; C = 100; NT = 7;  base = A2B; i = job - 101; kb = i / 7;  nt = i % 7; }
  else if (job < 169) { W = m1; K = 106; C = 150; NT = 10; base = M1B; i = job - 129; kb = i / 10; nt = i % 10; }
  else if (job < 204) { W = m2; K = 150; C = 100; NT = 7;  base = M2B; i = job - 169; kb = i / 7;  nt = i % 7; }
  else                { W = m3; K = 100; C = 100; NT = 7;  base = M3B; i = job - 204; kb = i / 7;  nt = i % 7; }
  const int r = lane & 15, g = lane >> 4;
  const int j = nt * 16 + r;
  uint hi[8], lo[8];
  for (int e = 0; e < 8; ++e) {
    int k = kb * 32 + g * 8 + e;
    float v = (k < K && j < C) ? W[k * C + j] : 0.f;
    uint bits = __builtin_bit_cast(uint, v);
    hi[e] = bits >> 16;
    float hf = __builtin_bit_cast(float, bits & 0xffff0000u);
    float lf = v - hf;
    lo[e] = __builtin_bit_cast(uint, lf) >> 16;
  }
  uint4 vh = { hi[0] | (hi[1] << 16), hi[2] | (hi[3] << 16),
               hi[4] | (hi[5] << 16), hi[6] | (hi[7] << 16) };
  uint4 vl = { lo[0] | (lo[1] << 16), lo[2] | (lo[3] << 16),
               lo[4] | (lo[5] << 16), lo[6] | (lo[7] << 16) };
  ws[(size_t)(base + (kb * NT + nt) * 2 + 0) * 64 + lane] = vh;
  ws[(size_t)(base + (kb * NT + nt) * 2 + 1) * 64 + lane] = vl;
}

// ---------------- generic MFMA dense layer ----------------
// MODE: 0 relu->planar, 1 linear->planar + gs-atomic,
//       2 relu+gpart->planar, 3 relu -> score shfl-reduce + sce atomic (no store)
template <int KB, int NT, int C, int MODE, int MTL, int ROWS, int RVALID, bool W8>
__device__ __forceinline__ void mfma_layer(
    char* pool, int inOff, int PKin, int outOff, int PKout,
    const bf8* __restrict__ wsB, const float* __restrict__ bias,
    const float* gpartL, float* gsL, float* sceL, const float* __restrict__ a3,
    int lane, int wid) {
  constexpr int NTP = (NT + 1) / 2;
  const int r = lane & 15, g = lane >> 4;
  const char* Ain = pool + inOff;
  const int pstrIn = ROWS * PKin * 2;
  int wlo, mtb, mte;
  if constexpr (W8) {
    wlo = wid & 3;
    const int whi = wid >> 2;
    mtb = whi ? 2 : 0; mte = whi ? MTL : 2;
  } else { wlo = wid; mtb = 0; mte = MTL; }
  for (int p = wlo; p < NTP; p += 4) {
    const int nt0 = 2 * p;
    const bool two = (nt0 + 1 < NT);
    bf8 bh0[KB], bl0[KB], bh1[KB], bl1[KB];
#pragma unroll
    for (int kb = 0; kb < KB; ++kb) {
      bh0[kb] = wsB[((kb * NT + nt0) * 2 + 0) * 64 + lane];
      bl0[kb] = wsB[((kb * NT + nt0) * 2 + 1) * 64 + lane];
      if (two) {
        bh1[kb] = wsB[((kb * NT + nt0 + 1) * 2 + 0) * 64 + lane];
        bl1[kb] = wsB[((kb * NT + nt0 + 1) * 2 + 1) * 64 + lane];
      }
    }
    for (int mt = mtb; mt < mte; ++mt) {
      int rA = mt * 16 + r;
      if constexpr (MTL * 16 > ROWS) { if (rA >= ROWS) rA = mt * 16 + (r & 7); }
      f4 acc0 = {0.f, 0.f, 0.f, 0.f}, acc1 = {0.f, 0.f, 0.f, 0.f};
      const char* aHi = Ain + rA * (PKin * 2) + g * 16;
      const char* aLo = aHi + pstrIn;
#pragma unroll
      for (int kb = 0; kb < KB; ++kb) {
        bf8 ah = *(const bf8*)(aHi + kb * 64);
        bf8 al = *(const bf8*)(aLo + kb * 64);
        acc0 = __builtin_amdgcn_mfma_f32_16x16x32_bf16(ah, bh0[kb], acc0, 0, 0, 0);
        if (two) acc1 = __builtin_amdgcn_mfma_f32_16x16x32_bf16(ah, bh1[kb], acc1, 0, 0, 0);
        acc0 = __builtin_amdgcn_mfma_f32_16x16x32_bf16(al, bh0[kb], acc0, 0, 0, 0);
        if (two) acc1 = __builtin_amdgcn_mfma_f32_16x16x32_bf16(al, bh1[kb], acc1, 0, 0, 0);
        acc0 = __builtin_amdgcn_mfma_f32_16x16x32_bf16(ah, bl0[kb], acc0, 0, 0, 0);
        if (two) acc1 = __builtin_amdgcn_mfma_f32_16x16x32_bf16(ah, bl1[kb], acc1, 0, 0, 0);
      }
#pragma unroll
      for (int t = 0; t < 2; ++t) {
        if (t && !two) break;
        const int nt = nt0 + t;
        const f4 acc = t ? acc1 : acc0;
        const int col = nt * 16 + r;
        const int rbase = mt * 16 + g * 4;
        const float bcol = (col < C) ? bias[col] : 0.f;
        float gp = 0.f;
        if constexpr (MODE == 2) {
          const int rb = rbase / 20;
          if (rb < NB && col < C) gp = gpartL[rb * 100 + col];
        }
        float a3c = 0.f;
        if constexpr (MODE == 3) { if (col < C) a3c = a3[col]; }
        float vsum = 0.f;
#pragma unroll
        for (int q = 0; q < 4; ++q) {
          const int orow = rbase + q;
          float v = 0.f;
          if (orow < RVALID && col < C) {
            v = acc[q] + bcol;
            if constexpr (MODE == 2) v += gp;
            if constexpr (MODE != 1) v = fmaxf(v, 0.f);
          }
          if constexpr (MODE == 3) {
            float val = v * a3c;
            val += __shfl_xor(val, 1);
            val += __shfl_xor(val, 2);
            val += __shfl_xor(val, 4);
            val += __shfl_xor(val, 8);
            if (r == 0 && orow < RVALID) atomicAdd(&sceL[orow], val);
          } else {
            vsum += v;
            if (orow < RVALID) {
              ushort* oHi = (ushort*)(pool + outOff) + orow * PKout + col;
              split_store(v, oHi, ROWS * PKout);
            }
          }
        }
        if constexpr (MODE == 1) {
          if (col < C && rbase < RVALID)
            atomicAdd(&gsL[(rbase / 20) * 100 + col], vsum);
        }
      }
    }
  }
}

// zero cols [112,128) of a planar buffer (epilogue covers [C,112) with 0s)
template <int ROWSZ, int PK>
__device__ __forceinline__ void zero_tail(char* pool, int off, int tid) {
  if (tid < 2 * ROWSZ) {
    int row = tid >> 1, pl = tid & 1;
    uint2* z = (uint2*)((ushort*)(pool + off) + (size_t)pl * ROWSZ * PK + row * PK + 112);
#pragma unroll
    for (int u = 0; u < 4; ++u) z[u] = uint2{0, 0};
  }
}

// ---------------- L1: A-fragments built in registers from state ----------------
__device__ __forceinline__ void l1_layer(
    const float* __restrict__ state, int b0, char* pool,
    const bf8* __restrict__ wsB, const float* __restrict__ bias,
    int lane, int wid) {
  const int r = lane & 15, g = lane >> 4;
  const int wlo = wid & 3, whi = wid >> 2;
  const int mtb = whi ? 2 : 0, mte = whi ? 3 : 2;
  for (int mt = mtb; mt < mte; ++mt) {
    const int rl = mt * 16 + r;
    bf8 ah = __builtin_bit_cast(bf8, (uint4){0, 0, 0, 0});
    bf8 al = ah;
    if (rl < NROWSR) {
      const float* sp = state + ((size_t)b0 * 20 + rl) * 13;
      uint hv[8], lv[8];
#pragma unroll
      for (int e = 0; e < 8; ++e) {
        int k = g * 8 + e;
        float v = (k < 13) ? sp[k] : 0.f;
        uint bits = __builtin_bit_cast(uint, v);
        hv[e] = bits >> 16;
        float hf = __builtin_bit_cast(float, bits & 0xffff0000u);
        lv[e] = __builtin_bit_cast(uint, v - hf) >> 16;
      }
      uint4 H = {hv[0] | (hv[1] << 16), hv[2] | (hv[3] << 16),
                 hv[4] | (hv[5] << 16), hv[6] | (hv[7] << 16)};
      uint4 L = {lv[0] | (lv[1] << 16), lv[2] | (lv[3] << 16),
                 lv[4] | (lv[5] << 16), lv[6] | (lv[7] << 16)};
      ah = __builtin_bit_cast(bf8, H);
      al = __builtin_bit_cast(bf8, L);
    }
    for (int p = wlo; p < 5; p += 4) {
      const int nt0 = 2 * p;
      bf8 bh0 = wsB[((nt0) * 2 + 0) * 64 + lane];
      bf8 bl0 = wsB[((nt0) * 2 + 1) * 64 + lane];
      bf8 bh1 = wsB[((nt0 + 1) * 2 + 0) * 64 + lane];
      bf8 bl1 = wsB[((nt0 + 1) * 2 + 1) * 64 + lane];
      f4 acc0 = {0.f, 0.f, 0.f, 0.f}, acc1 = {0.f, 0.f, 0.f, 0.f};
      acc0 = __builtin_amdgcn_mfma_f32_16x16x32_bf16(ah, bh0, acc0, 0, 0, 0);
      acc1 = __builtin_amdgcn_mfma_f32_16x16x32_bf16(ah, bh1, acc1, 0, 0, 0);
      acc0 = __builtin_amdgcn_mfma_f32_16x16x32_bf16(al, bh0, acc0, 0, 0, 0);
      acc1 = __builtin_amdgcn_mfma_f32_16x16x32_bf16(al, bh1, acc1, 0, 0, 0);
      acc0 = __builtin_amdgcn_mfma_f32_16x16x32_bf16(ah, bl0, acc0, 0, 0, 0);
      acc1 = __builtin_amdgcn_mfma_f32_16x16x32_bf16(ah, bl1, acc1, 0, 0, 0);
#pragma unroll
      for (int t = 0; t < 2; ++t) {
        const int nt = nt0 + t;
        const f4 acc = t ? acc1 : acc0;
        const int col = nt * 16 + r;
        const int rbase = mt * 16 + g * 4;
        const float bcol = (col < 150) ? bias[col] : 0.f;
#pragma unroll
        for (int q = 0; q < 4; ++q) {
          const int orow = rbase + q;
          if (orow < NROWSR) {
            float v = (col < 150) ? fmaxf(acc[q] + bcol, 0.f) : 0.f;
            ushort* oHi = (ushort*)(pool + H1_OFF) + orow * H1_PK + col;
            split_store(v, oHi, 40 * H1_PK);
          }
        }
      }
    }
  }
}

// ---------------- kernel1: MLP1 + attention -> joint ----------------
// NOTE: __launch_bounds__ arg2 is BLOCKS PER CU (CUDA semantics) on this
// toolchain: (512,4)->64 VGPR, (512,6)->40 VGPR (spill disaster, R4).
// (512,3): 24 waves/CU -> VGPR cap ~85; LDS 3*47040=141KB fits 160KB.
__global__ __launch_bounds__(NTHR, 3) void value_net_kernel(
    const float* __restrict__ state,
    const float* __restrict__ b1, const float* __restrict__ b2,
    const float* __restrict__ b3,
    const float* __restrict__ a1, const float* __restrict__ ab1,
    const float* __restrict__ ab2,
    const float* __restrict__ a3, const float* __restrict__ ab3,
    const uint4* __restrict__ ws, float* __restrict__ jointg) {
  __shared__ char pool[POOL1];
  __shared__ float gsL[200], gpartL[200], sceL[40], swL[40];

  const int tid = threadIdx.x;
  const int lane = tid & 63, wid = tid >> 6;
  const int b0 = blockIdx.x * NB;
  const bf8* wsb = (const bf8*)ws;

  // P1: L1 13->150 relu (A from state via regs) -> H1
  l1_layer(state, b0, pool, wsb + L1B * 64, b1, lane, wid);
  __syncthreads();

  // P2: zero gsL; zero H2 tail; L2 150->100 relu H1->H2
  if (tid < 200) gsL[tid] = 0.f;
  zero_tail<40, H2_PK>(pool, H2_OFF, tid);
  mfma_layer<5, 7, 100, 0, 3, 40, NROWSR, true>(
      pool, H1_OFF, H1_PK, H2_OFF, H2_PK, wsb + L2B * 64, b2,
      nullptr, nullptr, nullptr, nullptr, lane, wid);
  __syncthreads();

  // P3: zero FEAT tail; L3 100->100 linear H2->FEAT (+ gs atomics)
  zero_tail<40, FEAT_PK>(pool, FEAT_OFF, tid);
  mfma_layer<4, 7, 100, 1, 3, 40, NROWSR, true>(
      pool, H2_OFF, H2_PK, FEAT_OFF, FEAT_PK, wsb + L3B * 64, b3,
      nullptr, gsL, nullptr, nullptr, lane, wid);
  __syncthreads();

  // P4: gpart = (gs*0.05) @ a1[100:200]; zero sceL
  if (tid < 400) {
    const int b = tid / 200, rem = tid - b * 200;
    const int j = rem >> 1, half = rem & 1;
    float acc = 0.f;
    const float* gsb = gsL + b * 100;
    for (int k = half * 50; k < half * 50 + 50; ++k)
      acc += gsb[k] * a1[(100 + k) * 100 + j];
    acc += __shfl_xor(acc, 1);
    if (half == 0) gpartL[b * 100 + j] = acc * 0.05f;
  } else if (tid < 440) {
    sceL[tid - 400] = 0.f;
  }
  __syncthreads();

  // P5: zero S1 tail; A1 (feat half) + gpart, relu -> S1
  zero_tail<40, S1_PK>(pool, S1_OFF, tid);
  mfma_layer<4, 7, 100, 2, 3, 40, NROWSR, true>(
      pool, FEAT_OFF, FEAT_PK, S1_OFF, S1_PK, wsb + A1B * 64, ab1,
      gpartL, nullptr, nullptr, nullptr, lane, wid);
  __syncthreads();

  // P6: A2 relu + fold A3 dot -> sceL atomics (no planar out)
  mfma_layer<4, 7, 100, 3, 3, 40, NROWSR, true>(
      pool, S1_OFF, S1_PK, 0, 0, wsb + A2B * 64, ab2,
      nullptr, nullptr, sceL, a3, lane, wid);
  __syncthreads();

  // P7: softmax over n (relu(score+ab3))
  if (tid < NROWSR) {
    const int b = tid / 20, n = tid - b * 20;
    const float ab3v = ab3[0];
    float m = -1e30f;
    for (int i = 0; i < 20; ++i) m = fmaxf(m, relu_f(sceL[b * 20 + i] + ab3v));
    float sum = 0.f, mine = 0.f;
    for (int i = 0; i < 20; ++i) {
      float e = __expf(relu_f(sceL[b * 20 + i] + ab3v) - m);
      sum += e;
      if (i == n) mine = e;
    }
    swL[tid] = mine / sum;
  }
  __syncthreads();

  // P8: weighted feature + self -> jointg
  if (tid < 400) {
    const int b = tid / 200, rem = tid - b * 200;
    const int d = rem >> 1, half = rem & 1;
    const ushort* fh = (const ushort*)(pool + FEAT_OFF);
    const ushort* fl = fh + 40 * FEAT_PK;
    float acc = 0.f;
    for (int n = half * 10; n < half * 10 + 10; ++n) {
      const int rw = b * 20 + n;
      acc += swL[b * 20 + n] * (us2f(fh[rw * FEAT_PK + d]) + us2f(fl[rw * FEAT_PK + d]));
    }
    acc += __shfl_xor(acc, 1);
    if (half == 0) jointg[(size_t)(b0 + b) * 106 + 6 + d] = acc;
  } else if (tid < 412) {
    const int idx = tid - 400, b = idx / 6, i = idx - b * 6;
    jointg[(size_t)(b0 + b) * 106 + i] = state[(b0 + b) * 260 + i];
  }
}

// ---------------- kernel2: M-MLP GEMM over 16384 rows ----------------
__global__ __launch_bounds__(K2THR) void mlp2_kernel(
    const float* __restrict__ jointg,
    const float* __restrict__ mb1, const float* __restrict__ mb2,
    const float* __restrict__ mb3,
    const float* __restrict__ m4, const float* __restrict__ mb4,
    const uint4* __restrict__ ws, float* __restrict__ out) {
  __shared__ char pool[K2_POOL];
  __shared__ float m4L[100];
  const int tid = threadIdx.x, lane = tid & 63, wid = tid >> 6;
  const size_t r0 = (size_t)blockIdx.x * K2ROWS;
  const bf8* wsb = (const bf8*)ws;

  // stage joint -> planar hi/lo (PK=136, cols 106..135 zero); m4 -> LDS
  for (int i = tid; i < K2ROWS * 136; i += K2THR) {
    int row = i / 136, k = i - row * 136;
    float v = (k < 106) ? jointg[(r0 + row) * 106 + k] : 0.f;
    split_store(v, (ushort*)(pool + K2_JT_OFF) + row * 136 + k, K2ROWS * 136);
  }
  if (tid < 100) m4L[tid] = m4[tid];
  __syncthreads();

  // M1: 106->150 relu (joint PK136 -> v1 PK168)
  mfma_layer<4, 10, 150, 0, 4, K2ROWS, K2ROWS, false>(
      pool, K2_JT_OFF, 136, K2_V1_OFF, 168, wsb + M1B * 64, mb1,
      nullptr, nullptr, nullptr, nullptr, lane, wid);
  __syncthreads();

  // M2: 150->100 relu (v1 -> v2 @0, PK136)
  zero_tail<K2ROWS, 136>(pool, 0, tid);
  mfma_layer<5, 7, 100, 0, 4, K2ROWS, K2ROWS, false>(
      pool, K2_V1_OFF, 168, 0, 136, wsb + M2B * 64, mb2,
      nullptr, nullptr, nullptr, nullptr, lane, wid);
  __syncthreads();

  // M3: 100->100 relu (v2 -> v3 @V1_OFF, PK136)
  mfma_layer<4, 7, 100, 0, 4, K2ROWS, K2ROWS, false>(
      pool, 0, 136, K2_V1_OFF, 136, wsb + M3B * 64, mb3,
      nullptr, nullptr, nullptr, nullptr, lane, wid);
  __syncthreads();

  // M4: 100->1
  {
    const int row = tid >> 2, seg = tid & 3;
    const ushort* vh = (const ushort*)(pool + K2_V1_OFF);
    const ushort* vl = vh + K2ROWS * 136;
    float s = 0.f;
    for (int k = seg; k < 100; k += 4)
      s += (us2f(vh[row * 136 + k]) + us2f(vl[row * 136 + k])) * m4L[k];
    s += __shfl_xor(s, 1);
    s += __shfl_xor(s, 2);
    if (seg == 0) out[r0 + row] = s + mb4[0];
  }
}

extern "C" void kernel_launch(void* const* d_in, const int* in_sizes, int n_in,
                              void* d_out, int out_size, void* d_ws, size_t ws_size,
                              hipStream_t stream) {
  const float* state = (const float*)d_in[0];
  const float* w1 = (const float*)d_in[1];
  const float* b1 = (const float*)d_in[2];
  const float* w2 = (const float*)d_in[3];
  const float* b2 = (const float*)d_in[4];
  const float* w3 = (const float*)d_in[5];
  const float* b3 = (const float*)d_in[6];
  const float* a1 = (const float*)d_in[7];
  const float* ab1 = (const float*)d_in[8];
  const float* a2 = (const float*)d_in[9];
  const float* ab2 = (const float*)d_in[10];
  const float* a3 = (const float*)d_in[11];
  const float* ab3 = (const float*)d_in[12];
  const float* m1 = (const float*)d_in[13];
  const float* mb1 = (const float*)d_in[14];
  const float* m2 = (const float*)d_in[15];
  const float* mb2 = (const float*)d_in[16];
  const float* m3 = (const float*)d_in[17];
  const float* mb3 = (const float*)d_in[18];
  const float* m4 = (const float*)d_in[19];
  const float* mb4 = (const float*)d_in[20];
  float* out = (float*)d_out;
  uint4* ws = (uint4*)d_ws;
  float* jointg = (float*)d_ws + JOINT_F;

  prep_kernel<<<232, 64, 0, stream>>>(w1, w2, w3, a1, a2, m1, m2, m3, ws);

  const int B = in_sizes[0] / 260;  // 16384
  value_net_kernel<<<dim3(B / NB), dim3(NTHR), 0, stream>>>(
      state, b1, b2, b3, a1, ab1, ab2, a3, ab3, (const uint4*)ws, jointg);

  mlp2_kernel<<<dim3(B / K2ROWS), dim3(K2THR), 0, stream>>>(
      jointg, mb1, mb2, mb3, m4, mb4, (const uint4*)ws, out);
}

// Round 6
// 785.179 us; speedup vs baseline: 1.3330x; 1.0397x over previous
//
#include <hip/hip_runtime.h>
#include <math.h>

#define NTHR 512
#define NB 2              // batches per WG (kernel1)
#define NROWSR (NB * 20)  // 40 real rows

using bf8 = __attribute__((ext_vector_type(8))) short;
using f4  = __attribute__((ext_vector_type(4))) float;

// kernel1 LDS pool (bytes). Planar hi/lo bf16: [plane][40][PK], 4B/elem total.
#define H1_OFF 0
#define H1_PK 164        // 40*164*4 = 26240
#define H2_OFF 26240
#define H2_PK 132        // 40*132*4 = 21120 -> end 47360
#define FEAT_OFF 0       // aliases H1 (dead after P2)
#define FEAT_PK 132
#define S1_OFF 26240     // aliases H2 (dead after P3); tail zeros inherited from H2
#define S1_PK 132
#define XS_OFF 26240     // aliases H2 region during P0/P1 only (dead after P1)
#define XS_PK 40         // 40*40*4 = 6400
#define POOL1 47360

// ws fragment bases (1KB blocks; each (kb,p) = 2 blocks hi+lo)
#define L1B 0
#define L2B 20
#define L3B 90
#define A1B 146
#define A2B 202
#define M1B 258
#define M2B 338
#define M3B 408
#define JOINT_F 118784   // float offset of joint[16384][106] in ws

// kernel2
#define K2ROWS 32
#define K2THR 256
#define K2_JT_OFF 0      // 32*132*4 = 16896
#define K2_V1_OFF 16896  // 32*164*4 = 20992 -> end 37888
#define K2_POOL 37888

__device__ __forceinline__ float relu_f(float v) { return fmaxf(v, 0.f); }
__device__ __forceinline__ float us2f(ushort u) {
  return __builtin_bit_cast(float, (uint)u << 16);
}
__device__ __forceinline__ void split_store(float v, ushort* p, int pstride) {
  uint bits = __builtin_bit_cast(uint, v);
  float hf = __builtin_bit_cast(float, bits & 0xffff0000u);
  float lf = v - hf;
  p[0] = (ushort)(bits >> 16);
  p[pstride] = (ushort)(__builtin_bit_cast(uint, lf) >> 16);
}

// ---------------- prep: pack hi/lo bf16 W-fragments ----------------
// Frag (kb, p, plane): lane l holds out-feature j = p*16 + (l&15),
// k = kb*32 + (l>>4)*8 + e. Used as MFMA *A* operand (W^T).
__global__ __launch_bounds__(64) void prep_kernel(
    const float* __restrict__ w1, const float* __restrict__ w2,
    const float* __restrict__ w3, const float* __restrict__ a1,
    const float* __restrict__ a2, const float* __restrict__ m1,
    const float* __restrict__ m2, const float* __restrict__ m3,
    uint4* __restrict__ ws) {
  const int job = blockIdx.x;
  const int lane = threadIdx.x;
  const float* W;
  int K, C, NT, base, kb, nt, i;
  if (job < 10)       { W = w1; K = 13;  C = 150; NT = 10; base = L1B; kb = 0; nt = job; }
  else if (job < 45)  { W = w2; K = 150; C = 100; NT = 7;  base = L2B; i = job - 10;  kb = i / 7;  nt = i % 7; }
  else if (job < 73)  { W = w3; K = 100; C = 100; NT = 7;  base = L3B; i = job - 45;  kb = i / 7;  nt = i % 7; }
  else if (job < 101) { W = a1; K = 100; C = 100; NT = 7;  base = A1B; i = job - 73;  kb = i / 7;  nt = i % 7; }
  else if (job < 129) { W = a2; K = 100; C = 100; NT = 7;  base = A2B; i = job - 101; kb = i / 7;  nt = i % 7; }
  else if (job < 169) { W = m1; K = 106; C = 150; NT = 10; base = M1B; i = job - 129; kb = i / 10; nt = i % 10; }
  else if (job < 204) { W = m2; K = 150; C = 100; NT = 7;  base = M2B; i = job - 169; kb = i / 7;  nt = i % 7; }
  else                { W = m3; K = 100; C = 100; NT = 7;  base = M3B; i = job - 204; kb = i / 7;  nt = i % 7; }
  const int r = lane & 15, g = lane >> 4;
  const int j = nt * 16 + r;
  uint hi[8], lo[8];
  for (int e = 0; e < 8; ++e) {
    int k = kb * 32 + g * 8 + e;
    float v = (k < K && j < C) ? W[k * C + j] : 0.f;
    uint bits = __builtin_bit_cast(uint, v);
    hi[e] = bits >> 16;
    float hf = __builtin_bit_cast(float, bits & 0xffff0000u);
    float lf = v - hf;
    lo[e] = __builtin_bit_cast(uint, lf) >> 16;
  }
  uint4 vh = { hi[0] | (hi[1] << 16), hi[2] | (hi[3] << 16),
               hi[4] | (hi[5] << 16), hi[6] | (hi[7] << 16) };
  uint4 vl = { lo[0] | (lo[1] << 16), lo[2] | (lo[3] << 16),
               lo[4] | (lo[5] << 16), lo[6] | (lo[7] << 16) };
  ws[(size_t)(base + (kb * NT + nt) * 2 + 0) * 64 + lane] = vh;
  ws[(size_t)(base + (kb * NT + nt) * 2 + 1) * 64 + lane] = vl;
}

// guarded float4 from a C-element array at 4-aligned offset of4
__device__ __forceinline__ float4 load4_guard(const float* __restrict__ a, int of4, int C) {
  float4 v;
  if (of4 + 3 < C) v = *(const float4*)(a + of4);
  else {
    v.x = (of4 + 0 < C) ? a[of4 + 0] : 0.f;
    v.y = (of4 + 1 < C) ? a[of4 + 1] : 0.f;
    v.z = (of4 + 2 < C) ? a[of4 + 2] : 0.f;
    v.w = (of4 + 3 < C) ? a[of4 + 3] : 0.f;
  }
  return v;
}

// ---------------- MFMA dense layer, transposed output ----------------
// D = W^T * act^T: lane holds 4 out-features (of4..of4+3) of ONE act-row.
// MODE: 0 relu->planar, 1 linear->planar, 2 relu+gpart->planar,
//       3 relu + a3-dot -> sceL atomics (no store)
template <int KB, int NP, int C, int MODE, int NT2, int ROWS, int RVALID, int NWAVES>
__device__ __forceinline__ void mfma_layer2(
    char* pool, int inOff, int PKin, int outOff, int PKout,
    const bf8* __restrict__ wsB, const float* __restrict__ bias,
    const float* gpartL, float* sceL, const float* __restrict__ a3,
    int lane, int wid) {
  const int r = lane & 15, g = lane >> 4;
  const int pstr = ROWS * PKin * 2;
  for (int u = wid; u < NP * NT2; u += NWAVES) {
    const int p = u / NT2, nt2 = u % NT2;
    const int arow = nt2 * 16 + r;
    int arow_rd = arow;
    if constexpr (NT2 * 16 > ROWS) { if (arow_rd >= ROWS) arow_rd = nt2 * 16 + (r & 7); }
    const char* aHi = pool + inOff + arow_rd * (PKin * 2) + g * 16;
    const char* aLo = aHi + pstr;
    f4 accA = {0.f, 0.f, 0.f, 0.f}, accB = {0.f, 0.f, 0.f, 0.f};
#pragma unroll 2
    for (int kb = 0; kb < KB; ++kb) {
      bf8 wh = wsB[((kb * NP + p) * 2 + 0) * 64 + lane];
      bf8 wl = wsB[((kb * NP + p) * 2 + 1) * 64 + lane];
      bf8 ah = *(const bf8*)(aHi + kb * 64);
      bf8 al = *(const bf8*)(aLo + kb * 64);
      accA = __builtin_amdgcn_mfma_f32_16x16x32_bf16(wh, ah, accA, 0, 0, 0);
      accB = __builtin_amdgcn_mfma_f32_16x16x32_bf16(wl, ah, accB, 0, 0, 0);
      accA = __builtin_amdgcn_mfma_f32_16x16x32_bf16(wh, al, accA, 0, 0, 0);
    }
    const int of4 = p * 16 + g * 4;
    float4 b4 = load4_guard(bias, of4, C);
    float4 gp4 = {0.f, 0.f, 0.f, 0.f};
    if constexpr (MODE == 2) {
      const int b = (arow < RVALID) ? (arow / 20) : 0;
      if (of4 + 3 < C) gp4 = *(const float4*)(gpartL + b * 100 + of4);
    }
    float v[4];
#pragma unroll
    for (int q = 0; q < 4; ++q) {
      float x = accA[q] + accB[q] + (&b4.x)[q];
      if constexpr (MODE == 2) x += (&gp4.x)[q];
      if constexpr (MODE != 1) x = fmaxf(x, 0.f);
      const bool valid = (of4 + q < C) && (arow < RVALID);
      v[q] = valid ? x : 0.f;
    }
    if constexpr (MODE == 3) {
      float4 a34 = load4_guard(a3, of4, C);
      float partial = v[0] * a34.x + v[1] * a34.y + v[2] * a34.z + v[3] * a34.w;
      partial += __shfl_xor(partial, 16);
      partial += __shfl_xor(partial, 32);
      if (lane < 16 && arow < RVALID) atomicAdd(&sceL[arow], partial);
    } else {
      if (arow < RVALID) {
        uint b0 = __builtin_bit_cast(uint, v[0]);
        uint b1 = __builtin_bit_cast(uint, v[1]);
        uint b2 = __builtin_bit_cast(uint, v[2]);
        uint b3 = __builtin_bit_cast(uint, v[3]);
        float l0 = v[0] - __builtin_bit_cast(float, b0 & 0xffff0000u);
        float l1 = v[1] - __builtin_bit_cast(float, b1 & 0xffff0000u);
        float l2 = v[2] - __builtin_bit_cast(float, b2 & 0xffff0000u);
        float l3 = v[3] - __builtin_bit_cast(float, b3 & 0xffff0000u);
        uint2 H = { (b0 >> 16) | (b1 & 0xffff0000u), (b2 >> 16) | (b3 & 0xffff0000u) };
        uint2 L = { (__builtin_bit_cast(uint, l0) >> 16) | (__builtin_bit_cast(uint, l1) & 0xffff0000u),
                    (__builtin_bit_cast(uint, l2) >> 16) | (__builtin_bit_cast(uint, l3) & 0xffff0000u) };
        char* ob = pool + outOff + arow * (PKout * 2) + of4 * 2;
        *(uint2*)ob = H;
        *(uint2*)(ob + ROWS * PKout * 2) = L;
      }
    }
  }
}

// zero cols [112,128) of a PK=132 planar buffer
template <int ROWSZ>
__device__ __forceinline__ void zero_tail132(char* pool, int off, int tid) {
  if (tid < 2 * ROWSZ) {
    int row = tid >> 1, pl = tid & 1;
    uint2* z = (uint2*)((ushort*)(pool + off) + (size_t)pl * ROWSZ * 132 + row * 132 + 112);
#pragma unroll
    for (int u = 0; u < 4; ++u) z[u] = uint2{0, 0};
  }
}

// ---------------- kernel1: MLP1 + attention -> joint ----------------
// __launch_bounds__ arg2 evidence (R3/R4/R5): combined VGPR+AGPR cap = 512/arg2.
// arg2=6 -> cap ~85 -> 6 waves/SIMD; LDS 3*49KB fits -> 24 waves/CU.
// This kernel's loop keeps only wh,wl,ah,al + 2 acc live -> ~50 combined.
__global__ __launch_bounds__(NTHR, 6) void value_net_kernel(
    const float* __restrict__ state,
    const float* __restrict__ b1, const float* __restrict__ b2,
    const float* __restrict__ b3,
    const float* __restrict__ a1, const float* __restrict__ ab1,
    const float* __restrict__ ab2,
    const float* __restrict__ a3, const float* __restrict__ ab3,
    const uint4* __restrict__ ws, float* __restrict__ jointg) {
  __shared__ char pool[POOL1];
  __shared__ float gsL[200], gpartL[200], sceL[40], swL[40];

  const int tid = threadIdx.x;
  const int lane = tid & 63, wid = tid >> 6;
  const int b0 = blockIdx.x * NB;
  const bf8* wsb = (const bf8*)ws;

  // P0: stage state -> XS planar hi/lo (40 rows x PK40, cols 13..39 zero); zero sce
  for (int i = tid; i < 40 * XS_PK; i += NTHR) {
    int row = i / XS_PK, k = i - row * XS_PK;
    float v = (k < 13) ? state[(b0 * 20 + row) * 13 + k] : 0.f;
    split_store(v, (ushort*)(pool + XS_OFF) + row * XS_PK + k, 40 * XS_PK);
  }
  if (tid < 40) sceL[tid] = 0.f;
  __syncthreads();

  // P1: L1 13->150 relu  XS -> H1
  mfma_layer2<1, 10, 150, 0, 3, 40, NROWSR, 8>(
      pool, XS_OFF, XS_PK, H1_OFF, H1_PK, wsb + L1B * 64, b1,
      nullptr, nullptr, nullptr, lane, wid);
  __syncthreads();

  // P2: zero H2 tail; L2 150->100 relu  H1 -> H2
  zero_tail132<40>(pool, H2_OFF, tid);
  mfma_layer2<5, 7, 100, 0, 3, 40, NROWSR, 8>(
      pool, H1_OFF, H1_PK, H2_OFF, H2_PK, wsb + L2B * 64, b2,
      nullptr, nullptr, nullptr, lane, wid);
  __syncthreads();

  // P3: zero FEAT tail; L3 100->100 linear  H2 -> FEAT
  zero_tail132<40>(pool, FEAT_OFF, tid);
  mfma_layer2<4, 7, 100, 1, 3, 40, NROWSR, 8>(
      pool, H2_OFF, H2_PK, FEAT_OFF, FEAT_PK, wsb + L3B * 64, b3,
      nullptr, nullptr, nullptr, lane, wid);
  __syncthreads();

  // P4: gs = mean over n (x0.05)
  if (tid < NB * 100) {
    const int b = tid / 100, d = tid - b * 100;
    const ushort* fh = (const ushort*)(pool + FEAT_OFF);
    const ushort* fl = fh + 40 * FEAT_PK;
    float s = 0.f;
    for (int n = 0; n < 20; ++n) {
      int rw = b * 20 + n;
      s += us2f(fh[rw * FEAT_PK + d]) + us2f(fl[rw * FEAT_PK + d]);
    }
    gsL[b * 100 + d] = s * 0.05f;
  }
  __syncthreads();

  // P5: gpart = gs @ a1[100:200]
  if (tid < 400) {
    const int b = tid / 200, rem = tid - b * 200;
    const int j = rem >> 1, half = rem & 1;
    float acc = 0.f;
    const float* gsb = gsL + b * 100;
    for (int k = half * 50; k < half * 50 + 50; ++k)
      acc += gsb[k] * a1[(100 + k) * 100 + j];
    acc += __shfl_xor(acc, 1);
    if (half == 0) gpartL[b * 100 + j] = acc;
  }
  __syncthreads();

  // P6: A1 (feat half) + gpart, relu  FEAT -> S1 (tail zeros inherited from H2)
  mfma_layer2<4, 7, 100, 2, 3, 40, NROWSR, 8>(
      pool, FEAT_OFF, FEAT_PK, S1_OFF, S1_PK, wsb + A1B * 64, ab1,
      gpartL, nullptr, nullptr, lane, wid);
  __syncthreads();

  // P7: A2 relu + A3 dot folded -> sceL
  mfma_layer2<4, 7, 100, 3, 3, 40, NROWSR, 8>(
      pool, S1_OFF, S1_PK, 0, 0, wsb + A2B * 64, ab2,
      nullptr, sceL, a3, lane, wid);
  __syncthreads();

  // P8: softmax over n of relu(score + ab3)
  if (tid < NROWSR) {
    const int b = tid / 20, n = tid - b * 20;
    const float ab3v = ab3[0];
    float m = -1e30f;
    for (int i = 0; i < 20; ++i) m = fmaxf(m, relu_f(sceL[b * 20 + i] + ab3v));
    float sum = 0.f, mine = 0.f;
    for (int i = 0; i < 20; ++i) {
      float e = __expf(relu_f(sceL[b * 20 + i] + ab3v) - m);
      sum += e;
      if (i == n) mine = e;
    }
    swL[tid] = mine / sum;
  }
  __syncthreads();

  // P9: weighted feature + self -> jointg
  if (tid < 400) {
    const int b = tid / 200, rem = tid - b * 200;
    const int d = rem >> 1, half = rem & 1;
    const ushort* fh = (const ushort*)(pool + FEAT_OFF);
    const ushort* fl = fh + 40 * FEAT_PK;
    float acc = 0.f;
    for (int n = half * 10; n < half * 10 + 10; ++n) {
      const int rw = b * 20 + n;
      acc += swL[b * 20 + n] * (us2f(fh[rw * FEAT_PK + d]) + us2f(fl[rw * FEAT_PK + d]));
    }
    acc += __shfl_xor(acc, 1);
    if (half == 0) jointg[(size_t)(b0 + b) * 106 + 6 + d] = acc;
  } else if (tid < 412) {
    const int idx = tid - 400, b = idx / 6, i = idx - b * 6;
    jointg[(size_t)(b0 + b) * 106 + i] = state[(b0 + b) * 260 + i];
  }
}

// ---------------- kernel2: M-MLP GEMM over 16384 rows ----------------
__global__ __launch_bounds__(K2THR, 4) void mlp2_kernel(
    const float* __restrict__ jointg,
    const float* __restrict__ mb1, const float* __restrict__ mb2,
    const float* __restrict__ mb3,
    const float* __restrict__ m4, const float* __restrict__ mb4,
    const uint4* __restrict__ ws, float* __restrict__ out) {
  __shared__ char pool[K2_POOL];
  __shared__ float m4L[100];
  const int tid = threadIdx.x, lane = tid & 63, wid = tid >> 6;
  const size_t r0 = (size_t)blockIdx.x * K2ROWS;
  const bf8* wsb = (const bf8*)ws;

  // stage joint -> planar hi/lo (PK=132, cols 106..131 zero); m4 -> LDS
  for (int i = tid; i < K2ROWS * 132; i += K2THR) {
    int row = i / 132, k = i - row * 132;
    float v = (k < 106) ? jointg[(r0 + row) * 106 + k] : 0.f;
    split_store(v, (ushort*)(pool + K2_JT_OFF) + row * 132 + k, K2ROWS * 132);
  }
  if (tid < 100) m4L[tid] = m4[tid];
  __syncthreads();

  // M1: 106->150 relu (jt PK132 -> v1 PK164)
  mfma_layer2<4, 10, 150, 0, 2, K2ROWS, K2ROWS, 4>(
      pool, K2_JT_OFF, 132, K2_V1_OFF, 164, wsb + M1B * 64, mb1,
      nullptr, nullptr, nullptr, lane, wid);
  __syncthreads();

  // M2: zero v2 tail; 150->100 relu (v1 -> v2 @0 PK132)
  zero_tail132<K2ROWS>(pool, 0, tid);
  mfma_layer2<5, 7, 100, 0, 2, K2ROWS, K2ROWS, 4>(
      pool, K2_V1_OFF, 164, 0, 132, wsb + M2B * 64, mb2,
      nullptr, nullptr, nullptr, lane, wid);
  __syncthreads();

  // M3: 100->100 relu (v2 -> v3 @V1_OFF PK132)
  mfma_layer2<4, 7, 100, 0, 2, K2ROWS, K2ROWS, 4>(
      pool, 0, 132, K2_V1_OFF, 132, wsb + M3B * 64, mb3,
      nullptr, nullptr, nullptr, lane, wid);
  __syncthreads();

  // M4: 100->1 (8 segs per row)
  {
    const int row = tid >> 3, seg = tid & 7;
    const ushort* vh = (const ushort*)(pool + K2_V1_OFF);
    const ushort* vl = vh + K2ROWS * 132;
    float s = 0.f;
    for (int k = seg; k < 100; k += 8)
      s += (us2f(vh[row * 132 + k]) + us2f(vl[row * 132 + k])) * m4L[k];
    s += __shfl_xor(s, 1);
    s += __shfl_xor(s, 2);
    s += __shfl_xor(s, 4);
    if (seg == 0) out[r0 + row] = s + mb4[0];
  }
}

extern "C" void kernel_launch(void* const* d_in, const int* in_sizes, int n_in,
                              void* d_out, int out_size, void* d_ws, size_t ws_size,
                              hipStream_t stream) {
  const float* state = (const float*)d_in[0];
  const float* w1 = (const float*)d_in[1];
  const float* b1 = (const float*)d_in[2];
  const float* w2 = (const float*)d_in[3];
  const float* b2 = (const float*)d_in[4];
  const float* w3 = (const float*)d_in[5];
  const float* b3 = (const float*)d_in[6];
  const float* a1 = (const float*)d_in[7];
  const float* ab1 = (const float*)d_in[8];
  const float* a2 = (const float*)d_in[9];
  const float* ab2 = (const float*)d_in[10];
  const float* a3 = (const float*)d_in[11];
  const float* ab3 = (const float*)d_in[12];
  const float* m1 = (const float*)d_in[13];
  const float* mb1 = (const float*)d_in[14];
  const float* m2 = (const float*)d_in[15];
  const float* mb2 = (const float*)d_in[16];
  const float* m3 = (const float*)d_in[17];
  const float* mb3 = (const float*)d_in[18];
  const float* m4 = (const float*)d_in[19];
  const float* mb4 = (const float*)d_in[20];
  float* out = (float*)d_out;
  uint4* ws = (uint4*)d_ws;
  float* jointg = (float*)d_ws + JOINT_F;

  prep_kernel<<<232, 64, 0, stream>>>(w1, w2, w3, a1, a2, m1, m2, m3, ws);

  const int B = in_sizes[0] / 260;  // 16384
  value_net_kernel<<<dim3(B / NB), dim3(NTHR), 0, stream>>>(
      state, b1, b2, b3, a1, ab1, ab2, a3, ab3, (const uint4*)ws, jointg);

  mlp2_kernel<<<dim3(B / K2ROWS), dim3(K2THR), 0, stream>>>(
      jointg, mb1, mb2, mb3, m4, mb4, (const uint4*)ws, out);
}

// Round 7
// 749.946 us; speedup vs baseline: 1.3956x; 1.0470x over previous
//
#include <hip/hip_runtime.h>
#include <math.h>

#define NTHR 512
#define NB 2              // batches per WG (kernel1)
#define NROWSR (NB * 20)  // 40 real rows

using bf8 = __attribute__((ext_vector_type(8))) short;
using f4  = __attribute__((ext_vector_type(4))) float;

// kernel1 LDS pool (bytes). Planar hi/lo bf16: [plane][40][PK], 4B/elem total.
#define H1_OFF 0
#define H1_PK 164        // 40*164*4 = 26240
#define H2_OFF 26240
#define H2_PK 132        // 40*132*4 = 21120 -> end 47360
#define FEAT_OFF 0       // aliases H1 (dead after P2)
#define FEAT_PK 132
#define S1_OFF 26240     // aliases H2 (dead after P3); tail zeros inherited from H2
#define S1_PK 132
#define XS_OFF 26240     // aliases H2 region during P0/P1 only (dead after P1)
#define XS_PK 40         // 40*40*4 = 6400
#define POOL1 47360

// ws fragment bases (1KB blocks; each (kb,p) = 2 blocks hi+lo)
#define L1B 0
#define L2B 20
#define L3B 90
#define A1B 146
#define A2B 202
#define M1B 258
#define M2B 338
#define M3B 408
#define JOINT_F 118784   // float offset of joint[16384][106] in ws

// kernel2
#define K2ROWS 32
#define K2THR 256
#define K2_JT_OFF 0      // 32*132*4 = 16896
#define K2_V1_OFF 16896  // 32*164*4 = 20992 -> end 37888
#define K2_POOL 37888

__device__ __forceinline__ float relu_f(float v) { return fmaxf(v, 0.f); }
__device__ __forceinline__ float us2f(ushort u) {
  return __builtin_bit_cast(float, (uint)u << 16);
}
__device__ __forceinline__ void split_store(float v, ushort* p, int pstride) {
  uint bits = __builtin_bit_cast(uint, v);
  float hf = __builtin_bit_cast(float, bits & 0xffff0000u);
  float lf = v - hf;
  p[0] = (ushort)(bits >> 16);
  p[pstride] = (ushort)(__builtin_bit_cast(uint, lf) >> 16);
}

// ---------------- prep: pack hi/lo bf16 W-fragments ----------------
// Frag (kb, p, plane): lane l holds out-feature j = p*16 + (l&15),
// k = kb*32 + (l>>4)*8 + e. Used as MFMA *A* operand (W^T).
__global__ __launch_bounds__(64) void prep_kernel(
    const float* __restrict__ w1, const float* __restrict__ w2,
    const float* __restrict__ w3, const float* __restrict__ a1,
    const float* __restrict__ a2, const float* __restrict__ m1,
    const float* __restrict__ m2, const float* __restrict__ m3,
    uint4* __restrict__ ws) {
  const int job = blockIdx.x;
  const int lane = threadIdx.x;
  const float* W;
  int K, C, NT, base, kb, nt, i;
  if (job < 10)       { W = w1; K = 13;  C = 150; NT = 10; base = L1B; kb = 0; nt = job; }
  else if (job < 45)  { W = w2; K = 150; C = 100; NT = 7;  base = L2B; i = job - 10;  kb = i / 7;  nt = i % 7; }
  else if (job < 73)  { W = w3; K = 100; C = 100; NT = 7;  base = L3B; i = job - 45;  kb = i / 7;  nt = i % 7; }
  else if (job < 101) { W = a1; K = 100; C = 100; NT = 7;  base = A1B; i = job - 73;  kb = i / 7;  nt = i % 7; }
  else if (job < 129) { W = a2; K = 100; C = 100; NT = 7;  base = A2B; i = job - 101; kb = i / 7;  nt = i % 7; }
  else if (job < 169) { W = m1; K = 106; C = 150; NT = 10; base = M1B; i = job - 129; kb = i / 10; nt = i % 10; }
  else if (job < 204) { W = m2; K = 150; C = 100; NT = 7;  base = M2B; i = job - 169; kb = i / 7;  nt = i % 7; }
  else                { W = m3; K = 100; C = 100; NT = 7;  base = M3B; i = job - 204; kb = i / 7;  nt = i % 7; }
  const int r = lane & 15, g = lane >> 4;
  const int j = nt * 16 + r;
  uint hi[8], lo[8];
  for (int e = 0; e < 8; ++e) {
    int k = kb * 32 + g * 8 + e;
    float v = (k < K && j < C) ? W[k * C + j] : 0.f;
    uint bits = __builtin_bit_cast(uint, v);
    hi[e] = bits >> 16;
    float hf = __builtin_bit_cast(float, bits & 0xffff0000u);
    float lf = v - hf;
    lo[e] = __builtin_bit_cast(uint, lf) >> 16;
  }
  uint4 vh = { hi[0] | (hi[1] << 16), hi[2] | (hi[3] << 16),
               hi[4] | (hi[5] << 16), hi[6] | (hi[7] << 16) };
  uint4 vl = { lo[0] | (lo[1] << 16), lo[2] | (lo[3] << 16),
               lo[4] | (lo[5] << 16), lo[6] | (lo[7] << 16) };
  ws[(size_t)(base + (kb * NT + nt) * 2 + 0) * 64 + lane] = vh;
  ws[(size_t)(base + (kb * NT + nt) * 2 + 1) * 64 + lane] = vl;
}

// guarded float4 from a C-element array at 4-aligned offset of4
__device__ __forceinline__ float4 load4_guard(const float* __restrict__ a, int of4, int C) {
  float4 v;
  if (of4 + 3 < C) v = *(const float4*)(a + of4);
  else {
    v.x = (of4 + 0 < C) ? a[of4 + 0] : 0.f;
    v.y = (of4 + 1 < C) ? a[of4 + 1] : 0.f;
    v.z = (of4 + 2 < C) ? a[of4 + 2] : 0.f;
    v.w = (of4 + 3 < C) ? a[of4 + 3] : 0.f;
  }
  return v;
}

// ---------------- MFMA dense layer, transposed output, W preloaded ----------------
// Each wave owns out-feature group(s) p (p = wid, wid+NWAVES, ...); W-fragments
// for that p are loaded from global ONCE per layer into registers (KB*2 frags),
// then all NT2 act-row tiles run with only ds_read+MFMA on the critical path.
// D = W^T * act^T: lane holds 4 out-features (of4..of4+3) of ONE act-row.
// MODE: 0 relu->planar, 1 linear->planar, 2 relu+gpart->planar,
//       3 relu + a3-dot -> sceL atomics (no store)
template <int KB, int NP, int C, int MODE, int NT2, int ROWS, int RVALID, int NWAVES>
__device__ __forceinline__ void mfma_layer3(
    char* pool, int inOff, int PKin, int outOff, int PKout,
    const bf8* __restrict__ wsB, const float* __restrict__ bias,
    const float* gpartL, float* sceL, const float* __restrict__ a3,
    int lane, int wid) {
  const int r = lane & 15, g = lane >> 4;
  const int pstr = ROWS * PKin * 2;
  for (int p = wid; p < NP; p += NWAVES) {
    bf8 wh[KB], wl[KB];
#pragma unroll
    for (int kb = 0; kb < KB; ++kb) {
      wh[kb] = wsB[((kb * NP + p) * 2 + 0) * 64 + lane];
      wl[kb] = wsB[((kb * NP + p) * 2 + 1) * 64 + lane];
    }
    const int of4 = p * 16 + g * 4;
    const float4 b4 = load4_guard(bias, of4, C);
    float4 a34 = {0.f, 0.f, 0.f, 0.f};
    if constexpr (MODE == 3) a34 = load4_guard(a3, of4, C);
#pragma unroll
    for (int nt2 = 0; nt2 < NT2; ++nt2) {
      const int arow = nt2 * 16 + r;
      int arow_rd = arow;
      if constexpr (NT2 * 16 > ROWS) { if (arow_rd >= ROWS) arow_rd = nt2 * 16 + (r & 7); }
      const char* aHi = pool + inOff + arow_rd * (PKin * 2) + g * 16;
      const char* aLo = aHi + pstr;
      f4 accA = {0.f, 0.f, 0.f, 0.f}, accB = {0.f, 0.f, 0.f, 0.f};
#pragma unroll
      for (int kb = 0; kb < KB; ++kb) {
        bf8 ah = *(const bf8*)(aHi + kb * 64);
        bf8 al = *(const bf8*)(aLo + kb * 64);
        accA = __builtin_amdgcn_mfma_f32_16x16x32_bf16(wh[kb], ah, accA, 0, 0, 0);
        accB = __builtin_amdgcn_mfma_f32_16x16x32_bf16(wl[kb], ah, accB, 0, 0, 0);
        accA = __builtin_amdgcn_mfma_f32_16x16x32_bf16(wh[kb], al, accA, 0, 0, 0);
      }
      float4 gp4 = {0.f, 0.f, 0.f, 0.f};
      if constexpr (MODE == 2) {
        const int b = (arow < RVALID) ? (arow / 20) : 0;
        if (of4 + 3 < C) gp4 = *(const float4*)(gpartL + b * 100 + of4);
      }
      float v[4];
#pragma unroll
      for (int q = 0; q < 4; ++q) {
        float x = accA[q] + accB[q] + (&b4.x)[q];
        if constexpr (MODE == 2) x += (&gp4.x)[q];
        if constexpr (MODE != 1) x = fmaxf(x, 0.f);
        const bool valid = (of4 + q < C) && (arow < RVALID);
        v[q] = valid ? x : 0.f;
      }
      if constexpr (MODE == 3) {
        float partial = v[0] * a34.x + v[1] * a34.y + v[2] * a34.z + v[3] * a34.w;
        partial += __shfl_xor(partial, 16);
        partial += __shfl_xor(partial, 32);
        if (lane < 16 && arow < RVALID) atomicAdd(&sceL[arow], partial);
      } else {
        if (arow < RVALID) {
          uint c0 = __builtin_bit_cast(uint, v[0]);
          uint c1 = __builtin_bit_cast(uint, v[1]);
          uint c2 = __builtin_bit_cast(uint, v[2]);
          uint c3 = __builtin_bit_cast(uint, v[3]);
          float l0 = v[0] - __builtin_bit_cast(float, c0 & 0xffff0000u);
          float l1 = v[1] - __builtin_bit_cast(float, c1 & 0xffff0000u);
          float l2 = v[2] - __builtin_bit_cast(float, c2 & 0xffff0000u);
          float l3 = v[3] - __builtin_bit_cast(float, c3 & 0xffff0000u);
          uint2 H = { (c0 >> 16) | (c1 & 0xffff0000u), (c2 >> 16) | (c3 & 0xffff0000u) };
          uint2 L = { (__builtin_bit_cast(uint, l0) >> 16) | (__builtin_bit_cast(uint, l1) & 0xffff0000u),
                      (__builtin_bit_cast(uint, l2) >> 16) | (__builtin_bit_cast(uint, l3) & 0xffff0000u) };
          char* ob = pool + outOff + arow * (PKout * 2) + of4 * 2;
          *(uint2*)ob = H;
          *(uint2*)(ob + ROWS * PKout * 2) = L;
        }
      }
    }
  }
}

// zero cols [112,128) of a PK=132 planar buffer
template <int ROWSZ>
__device__ __forceinline__ void zero_tail132(char* pool, int off, int tid) {
  if (tid < 2 * ROWSZ) {
    int row = tid >> 1, pl = tid & 1;
    uint2* z = (uint2*)((ushort*)(pool + off) + (size_t)pl * ROWSZ * 132 + row * 132 + 112);
#pragma unroll
    for (int u = 0; u < 4; ++u) z[u] = uint2{0, 0};
  }
}

// ---------------- kernel1: MLP1 + attention -> joint ----------------
// __launch_bounds__ arg2: combined VGPR+AGPR cap ~= 512/arg2 (R3..R6 evidence).
// arg2=6 -> cap ~85; LDS 3*49.7KB -> 3 blocks/CU, 24 waves/CU (R6: occ 69%).
// Live set here: wh/wl[KB<=5]=40 + ah/al 8 + acc 8 + epilogue ~20 -> ~80.
__global__ __launch_bounds__(NTHR, 6) void value_net_kernel(
    const float* __restrict__ state,
    const float* __restrict__ b1, const float* __restrict__ b2,
    const float* __restrict__ b3,
    const float* __restrict__ a1, const float* __restrict__ ab1,
    const float* __restrict__ ab2,
    const float* __restrict__ a3, const float* __restrict__ ab3,
    const uint4* __restrict__ ws, float* __restrict__ jointg) {
  __shared__ char pool[POOL1];
  __shared__ float gsL[200], gpartL[200], sceL[40], swL[40];

  const int tid = threadIdx.x;
  const int lane = tid & 63, wid = tid >> 6;
  const int b0 = blockIdx.x * NB;
  const bf8* wsb = (const bf8*)ws;

  // P0: stage state -> XS planar hi/lo (40 rows x PK40, cols 13..39 zero); zero sce
  for (int i = tid; i < 40 * XS_PK; i += NTHR) {
    int row = i / XS_PK, k = i - row * XS_PK;
    float v = (k < 13) ? state[(b0 * 20 + row) * 13 + k] : 0.f;
    split_store(v, (ushort*)(pool + XS_OFF) + row * XS_PK + k, 40 * XS_PK);
  }
  if (tid < 40) sceL[tid] = 0.f;
  __syncthreads();

  // P1: L1 13->150 relu  XS -> H1
  mfma_layer3<1, 10, 150, 0, 3, 40, NROWSR, 8>(
      pool, XS_OFF, XS_PK, H1_OFF, H1_PK, wsb + L1B * 64, b1,
      nullptr, nullptr, nullptr, lane, wid);
  __syncthreads();

  // P2: zero H2 tail; L2 150->100 relu  H1 -> H2
  zero_tail132<40>(pool, H2_OFF, tid);
  mfma_layer3<5, 7, 100, 0, 3, 40, NROWSR, 8>(
      pool, H1_OFF, H1_PK, H2_OFF, H2_PK, wsb + L2B * 64, b2,
      nullptr, nullptr, nullptr, lane, wid);
  __syncthreads();

  // P3: zero FEAT tail; L3 100->100 linear  H2 -> FEAT
  zero_tail132<40>(pool, FEAT_OFF, tid);
  mfma_layer3<4, 7, 100, 1, 3, 40, NROWSR, 8>(
      pool, H2_OFF, H2_PK, FEAT_OFF, FEAT_PK, wsb + L3B * 64, b3,
      nullptr, nullptr, nullptr, lane, wid);
  __syncthreads();

  // P4: gs = mean over n (x0.05)
  if (tid < NB * 100) {
    const int b = tid / 100, d = tid - b * 100;
    const ushort* fh = (const ushort*)(pool + FEAT_OFF);
    const ushort* fl = fh + 40 * FEAT_PK;
    float s = 0.f;
    for (int n = 0; n < 20; ++n) {
      int rw = b * 20 + n;
      s += us2f(fh[rw * FEAT_PK + d]) + us2f(fl[rw * FEAT_PK + d]);
    }
    gsL[b * 100 + d] = s * 0.05f;
  }
  __syncthreads();

  // P5: gpart = gs @ a1[100:200]
  if (tid < 400) {
    const int b = tid / 200, rem = tid - b * 200;
    const int j = rem >> 1, half = rem & 1;
    float acc = 0.f;
    const float* gsb = gsL + b * 100;
    for (int k = half * 50; k < half * 50 + 50; ++k)
      acc += gsb[k] * a1[(100 + k) * 100 + j];
    acc += __shfl_xor(acc, 1);
    if (half == 0) gpartL[b * 100 + j] = acc;
  }
  __syncthreads();

  // P6: A1 (feat half) + gpart, relu  FEAT -> S1 (tail zeros inherited from H2)
  mfma_layer3<4, 7, 100, 2, 3, 40, NROWSR, 8>(
      pool, FEAT_OFF, FEAT_PK, S1_OFF, S1_PK, wsb + A1B * 64, ab1,
      gpartL, nullptr, nullptr, lane, wid);
  __syncthreads();

  // P7: A2 relu + A3 dot folded -> sceL
  mfma_layer3<4, 7, 100, 3, 3, 40, NROWSR, 8>(
      pool, S1_OFF, S1_PK, 0, 0, wsb + A2B * 64, ab2,
      nullptr, sceL, a3, lane, wid);
  __syncthreads();

  // P8: softmax over n of relu(score + ab3)
  if (tid < NROWSR) {
    const int b = tid / 20, n = tid - b * 20;
    const float ab3v = ab3[0];
    float m = -1e30f;
    for (int i = 0; i < 20; ++i) m = fmaxf(m, relu_f(sceL[b * 20 + i] + ab3v));
    float sum = 0.f, mine = 0.f;
    for (int i = 0; i < 20; ++i) {
      float e = __expf(relu_f(sceL[b * 20 + i] + ab3v) - m);
      sum += e;
      if (i == n) mine = e;
    }
    swL[tid] = mine / sum;
  }
  __syncthreads();

  // P9: weighted feature + self -> jointg
  if (tid < 400) {
    const int b = tid / 200, rem = tid - b * 200;
    const int d = rem >> 1, half = rem & 1;
    const ushort* fh = (const ushort*)(pool + FEAT_OFF);
    const ushort* fl = fh + 40 * FEAT_PK;
    float acc = 0.f;
    for (int n = half * 10; n < half * 10 + 10; ++n) {
      const int rw = b * 20 + n;
      acc += swL[b * 20 + n] * (us2f(fh[rw * FEAT_PK + d]) + us2f(fl[rw * FEAT_PK + d]));
    }
    acc += __shfl_xor(acc, 1);
    if (half == 0) jointg[(size_t)(b0 + b) * 106 + 6 + d] = acc;
  } else if (tid < 412) {
    const int idx = tid - 400, b = idx / 6, i = idx - b * 6;
    jointg[(size_t)(b0 + b) * 106 + i] = state[(b0 + b) * 260 + i];
  }
}

// ---------------- kernel2: M-MLP GEMM over 16384 rows ----------------
__global__ __launch_bounds__(K2THR, 4) void mlp2_kernel(
    const float* __restrict__ jointg,
    const float* __restrict__ mb1, const float* __restrict__ mb2,
    const float* __restrict__ mb3,
    const float* __restrict__ m4, const float* __restrict__ mb4,
    const uint4* __restrict__ ws, float* __restrict__ out) {
  __shared__ char pool[K2_POOL];
  __shared__ float m4L[100];
  const int tid = threadIdx.x, lane = tid & 63, wid = tid >> 6;
  const size_t r0 = (size_t)blockIdx.x * K2ROWS;
  const bf8* wsb = (const bf8*)ws;

  // stage joint -> planar hi/lo (PK=132, cols 106..131 zero); m4 -> LDS
  for (int i = tid; i < K2ROWS * 132; i += K2THR) {
    int row = i / 132, k = i - row * 132;
    float v = (k < 106) ? jointg[(r0 + row) * 106 + k] : 0.f;
    split_store(v, (ushort*)(pool + K2_JT_OFF) + row * 132 + k, K2ROWS * 132);
  }
  if (tid < 100) m4L[tid] = m4[tid];
  __syncthreads();

  // M1: 106->150 relu (jt PK132 -> v1 PK164)
  mfma_layer3<4, 10, 150, 0, 2, K2ROWS, K2ROWS, 4>(
      pool, K2_JT_OFF, 132, K2_V1_OFF, 164, wsb + M1B * 64, mb1,
      nullptr, nullptr, nullptr, lane, wid);
  __syncthreads();

  // M2: zero v2 tail; 150->100 relu (v1 -> v2 @0 PK132)
  zero_tail132<K2ROWS>(pool, 0, tid);
  mfma_layer3<5, 7, 100, 0, 2, K2ROWS, K2ROWS, 4>(
      pool, K2_V1_OFF, 164, 0, 132, wsb + M2B * 64, mb2,
      nullptr, nullptr, nullptr, lane, wid);
  __syncthreads();

  // M3: 100->100 relu (v2 -> v3 @V1_OFF PK132)
  mfma_layer3<4, 7, 100, 0, 2, K2ROWS, K2ROWS, 4>(
      pool, 0, 132, K2_V1_OFF, 132, wsb + M3B * 64, mb3,
      nullptr, nullptr, nullptr, lane, wid);
  __syncthreads();

  // M4: 100->1 (8 segs per row)
  {
    const int row = tid >> 3, seg = tid & 7;
    const ushort* vh = (const ushort*)(pool + K2_V1_OFF);
    const ushort* vl = vh + K2ROWS * 132;
    float s = 0.f;
    for (int k = seg; k < 100; k += 8)
      s += (us2f(vh[row * 132 + k]) + us2f(vl[row * 132 + k])) * m4L[k];
    s += __shfl_xor(s, 1);
    s += __shfl_xor(s, 2);
    s += __shfl_xor(s, 4);
    if (seg == 0) out[r0 + row] = s + mb4[0];
  }
}

extern "C" void kernel_launch(void* const* d_in, const int* in_sizes, int n_in,
                              void* d_out, int out_size, void* d_ws, size_t ws_size,
                              hipStream_t stream) {
  const float* state = (const float*)d_in[0];
  const float* w1 = (const float*)d_in[1];
  const float* b1 = (const float*)d_in[2];
  const float* w2 = (const float*)d_in[3];
  const float* b2 = (const float*)d_in[4];
  const float* w3 = (const float*)d_in[5];
  const float* b3 = (const float*)d_in[6];
  const float* a1 = (const float*)d_in[7];
  const float* ab1 = (const float*)d_in[8];
  const float* a2 = (const float*)d_in[9];
  const float* ab2 = (const float*)d_in[10];
  const float* a3 = (const float*)d_in[11];
  const float* ab3 = (const float*)d_in[12];
  const float* m1 = (const float*)d_in[13];
  const float* mb1 = (const float*)d_in[14];
  const float* m2 = (const float*)d_in[15];
  const float* mb2 = (const float*)d_in[16];
  const float* m3 = (const float*)d_in[17];
  const float* mb3 = (const float*)d_in[18];
  const float* m4 = (const float*)d_in[19];
  const float* mb4 = (const float*)d_in[20];
  float* out = (float*)d_out;
  uint4* ws = (uint4*)d_ws;
  float* jointg = (float*)d_ws + JOINT_F;

  prep_kernel<<<232, 64, 0, stream>>>(w1, w2, w3, a1, a2, m1, m2, m3, ws);

  const int B = in_sizes[0] / 260;  // 16384
  value_net_kernel<<<dim3(B / NB), dim3(NTHR), 0, stream>>>(
      state, b1, b2, b3, a1, ab1, ab2, a3, ab3, (const uint4*)ws, jointg);

  mlp2_kernel<<<dim3(B / K2ROWS), dim3(K2THR), 0, stream>>>(
      jointg, mb1, mb2, mb3, m4, mb4, (const uint4*)ws, out);
}

// Round 8
// 416.594 us; speedup vs baseline: 2.5124x; 1.8002x over previous
//
#include <hip/hip_runtime.h>
#include <math.h>

#define NTHR 512
#define NB 2              // batches per WG (kernel1)
#define NROWSR (NB * 20)  // 40 real rows

using bf8 = __attribute__((ext_vector_type(8))) short;
using f4  = __attribute__((ext_vector_type(4))) float;

// kernel1 LDS pool (bytes). Planar hi/lo bf16: [plane][40][PK].
// PK chosen so row stride (PK*2) is a multiple of 16B: 168->336, 136->272.
#define H1_OFF 0
#define H1_PK 168        // 40*168*4 = 26880
#define H2_OFF 26880
#define H2_PK 136        // 40*136*4 = 21760 -> end 48640
#define FEAT_OFF 0       // aliases H1 (dead after L2)
#define FEAT_PK 136
#define S1_OFF 26880     // aliases H2 (dead after L3)
#define S1_PK 136
#define POOL1 48640

// ws fragment bases (1KB blocks; each (kb,nt) = 2 blocks hi+lo)
#define L1B 0
#define L2B 20
#define L3B 90
#define A1B 146
#define A2B 202
#define M1B 258
#define M2B 338
#define M3B 408
#define JOINT_F 118784   // float offset of joint[16384][106] in ws

// kernel2 (R3-proven config, aligned PKs)
#define K2ROWS 64
#define K2THR 256
#define K2_JT_OFF 0      // 64*136*4 = 34816
#define K2_V1_OFF 34816  // 64*168*4 = 43008 -> end 77824
#define K2_POOL 77824

__device__ __forceinline__ float relu_f(float v) { return fmaxf(v, 0.f); }
__device__ __forceinline__ float us2f(ushort u) {
  return __builtin_bit_cast(float, (uint)u << 16);
}
__device__ __forceinline__ void split_store(float v, ushort* p, int pstride) {
  uint bits = __builtin_bit_cast(uint, v);
  float hf = __builtin_bit_cast(float, bits & 0xffff0000u);
  float lf = v - hf;
  p[0] = (ushort)(bits >> 16);
  p[pstride] = (ushort)(__builtin_bit_cast(uint, lf) >> 16);
}

// ---------------- prep: pack hi/lo bf16 weight B-fragments ----------------
// Frag (kb, nt, plane): lane l holds out-feature j = nt*16 + (l&15),
// k = kb*32 + (l>>4)*8 + e  (16B per lane).
__global__ __launch_bounds__(64) void prep_kernel(
    const float* __restrict__ w1, const float* __restrict__ w2,
    const float* __restrict__ w3, const float* __restrict__ a1,
    const float* __restrict__ a2, const float* __restrict__ m1,
    const float* __restrict__ m2, const float* __restrict__ m3,
    uint4* __restrict__ ws) {
  const int job = blockIdx.x;
  const int lane = threadIdx.x;
  const float* W;
  int K, C, NT, base, kb, nt, i;
  if (job < 10)       { W = w1; K = 13;  C = 150; NT = 10; base = L1B; kb = 0; nt = job; }
  else if (job < 45)  { W = w2; K = 150; C = 100; NT = 7;  base = L2B; i = job - 10;  kb = i / 7;  nt = i % 7; }
  else if (job < 73)  { W = w3; K = 100; C = 100; NT = 7;  base = L3B; i = job - 45;  kb = i / 7;  nt = i % 7; }
  else if (job < 101) { W = a1; K = 100; C = 100; NT = 7;  base = A1B; i = job - 73;  kb = i / 7;  nt = i % 7; }
  else if (job < 129) { W = a2; K = 100; C = 100; NT = 7;  base = A2B; i = job - 101; kb = i / 7;  nt = i % 7; }
  else if (job < 169) { W = m1; K = 106; C = 150; NT = 10; base = M1B; i = job - 129; kb = i / 10; nt = i % 10; }
  else if (job < 204) { W = m2; K = 150; C = 100; NT = 7;  base = M2B; i = job - 169; kb = i / 7;  nt = i % 7; }
  else                { W = m3; K = 100; C = 100; NT = 7;  base = M3B; i = job - 204; kb = i / 7;  nt = i % 7; }
  const int r = lane & 15, g = lane >> 4;
  const int j = nt * 16 + r;
  uint hi[8], lo[8];
  for (int e = 0; e < 8; ++e) {
    int k = kb * 32 + g * 8 + e;
    float v = (k < K && j < C) ? W[k * C + j] : 0.f;
    uint bits = __builtin_bit_cast(uint, v);
    hi[e] = bits >> 16;
    float hf = __builtin_bit_cast(float, bits & 0xffff0000u);
    float lf = v - hf;
    lo[e] = __builtin_bit_cast(uint, lf) >> 16;
  }
  uint4 vh = { hi[0] | (hi[1] << 16), hi[2] | (hi[3] << 16),
               hi[4] | (hi[5] << 16), hi[6] | (hi[7] << 16) };
  uint4 vl = { lo[0] | (lo[1] << 16), lo[2] | (lo[3] << 16),
               lo[4] | (lo[5] << 16), lo[6] | (lo[7] << 16) };
  ws[(size_t)(base + (kb * NT + nt) * 2 + 0) * 64 + lane] = vh;
  ws[(size_t)(base + (kb * NT + nt) * 2 + 1) * 64 + lane] = vl;
}

// ---------------- R3-style MFMA dense layer (act-as-A, weights-as-B) ----------------
// D-layout: col (out-feature) = lane&15 (+nt*16), row (act row) = (lane>>4)*4+q (+mt*16).
// MODE: 0 relu->planar, 1 linear->planar, 2 relu+gpart->planar,
//       3 relu + a3-dot fold -> sceL atomics (no store)
// W8: 8-wave split (wlo=wid&3 picks nt-pair, wid>>2 splits mt); else wlo=wid.
// p-loop stride is 4 in both uses (8-wave kernel1 W8, 4-wave kernel2).
template <int KB, int NT, int C, int MODE, int MTL, int ROWS, int RVALID, bool W8>
__device__ __forceinline__ void mfma_layer(
    char* pool, int inOff, int PKin, int outOff, int PKout,
    const bf8* __restrict__ wsB, const float* __restrict__ bias,
    const float* gpartL, float* sceL, const float* __restrict__ a3,
    int lane, int wid) {
  constexpr int NTP = (NT + 1) / 2;
  const int r = lane & 15, g = lane >> 4;
  const char* Ain = pool + inOff;
  const int pstr = ROWS * PKin * 2;
  int wlo, mtb, mte;
  if constexpr (W8) {
    wlo = wid & 3;
    const int whi = wid >> 2;
    mtb = whi ? 2 : 0; mte = whi ? MTL : 2;
  } else { wlo = wid; mtb = 0; mte = MTL; }
  for (int p = wlo; p < NTP; p += 4) {
    const int nt0 = 2 * p;
    const bool two = (nt0 + 1 < NT);
    bf8 bh0[KB], bl0[KB], bh1[KB], bl1[KB];
#pragma unroll
    for (int kb = 0; kb < KB; ++kb) {
      bh0[kb] = wsB[((kb * NT + nt0) * 2 + 0) * 64 + lane];
      bl0[kb] = wsB[((kb * NT + nt0) * 2 + 1) * 64 + lane];
      if (two) {
        bh1[kb] = wsB[((kb * NT + nt0 + 1) * 2 + 0) * 64 + lane];
        bl1[kb] = wsB[((kb * NT + nt0 + 1) * 2 + 1) * 64 + lane];
      }
    }
    for (int mt = mtb; mt < mte; ++mt) {
      int rA = mt * 16 + r;
      if constexpr (MTL * 16 > ROWS) { if (rA >= ROWS) rA = mt * 16 + (r & 7); }
      f4 acc0 = {0.f, 0.f, 0.f, 0.f}, acc1 = {0.f, 0.f, 0.f, 0.f};
      const char* aHi = Ain + rA * (PKin * 2) + g * 16;
      const char* aLo = aHi + pstr;
#pragma unroll
      for (int kb = 0; kb < KB; ++kb) {
        bf8 ah = *(const bf8*)(aHi + kb * 64);
        bf8 al = *(const bf8*)(aLo + kb * 64);
        acc0 = __builtin_amdgcn_mfma_f32_16x16x32_bf16(ah, bh0[kb], acc0, 0, 0, 0);
        if (two) acc1 = __builtin_amdgcn_mfma_f32_16x16x32_bf16(ah, bh1[kb], acc1, 0, 0, 0);
        acc0 = __builtin_amdgcn_mfma_f32_16x16x32_bf16(al, bh0[kb], acc0, 0, 0, 0);
        if (two) acc1 = __builtin_amdgcn_mfma_f32_16x16x32_bf16(al, bh1[kb], acc1, 0, 0, 0);
        acc0 = __builtin_amdgcn_mfma_f32_16x16x32_bf16(ah, bl0[kb], acc0, 0, 0, 0);
        if (two) acc1 = __builtin_amdgcn_mfma_f32_16x16x32_bf16(ah, bl1[kb], acc1, 0, 0, 0);
      }
#pragma unroll
      for (int t = 0; t < 2; ++t) {
        if (t && !two) break;
        const int nt = nt0 + t;
        const f4 acc = t ? acc1 : acc0;
        const int col = nt * 16 + r;
        const int rbase = mt * 16 + g * 4;
        const float bcol = (col < C) ? bias[col] : 0.f;
        float gp = 0.f;
        if constexpr (MODE == 2) {
          if (col < C && rbase < RVALID) gp = gpartL[(rbase / 20) * 100 + col];
        }
        float a3c = 0.f;
        if constexpr (MODE == 3) { if (col < C) a3c = a3[col]; }
#pragma unroll
        for (int q = 0; q < 4; ++q) {
          const int orow = rbase + q;
          float v = 0.f;
          if (orow < RVALID && col < C) {
            v = acc[q] + bcol;
            if constexpr (MODE == 2) v += gp;
            if constexpr (MODE != 1) v = fmaxf(v, 0.f);
          }
          if constexpr (MODE == 3) {
            float val = v * a3c;
            val += __shfl_xor(val, 1);
            val += __shfl_xor(val, 2);
            val += __shfl_xor(val, 4);
            val += __shfl_xor(val, 8);
            if (r == 0 && orow < RVALID) atomicAdd(&sceL[orow], val);
          } else {
            if (orow < RVALID) {
              ushort* oHi = (ushort*)(pool + outOff) + orow * PKout + col;
              split_store(v, oHi, ROWS * PKout);
            }
          }
        }
      }
    }
  }
}

// zero cols [112,128) of a 40/64-row PK=136 planar buffer (epilogue covers [C,112))
template <int ROWSZ>
__device__ __forceinline__ void zero_tail136(char* pool, int off, int tid) {
  if (tid < 2 * ROWSZ) {
    int row = tid >> 1, pl = tid & 1;
    uint2* z = (uint2*)((ushort*)(pool + off) + (size_t)pl * ROWSZ * 136 + row * 136 + 112);
#pragma unroll
    for (int u = 0; u < 4; ++u) z[u] = uint2{0, 0};
  }
}

// ---------------- L1: A-fragments built in registers from state ----------------
__device__ __forceinline__ void l1_layer(
    const float* __restrict__ state, int b0, char* pool,
    const bf8* __restrict__ wsB, const float* __restrict__ bias,
    int lane, int wid) {
  const int r = lane & 15, g = lane >> 4;
  const int wlo = wid & 3, whi = wid >> 2;
  const int mtb = whi ? 2 : 0, mte = whi ? 3 : 2;
  for (int p = wlo; p < 5; p += 4) {
    const int nt0 = 2 * p;
    bf8 bh0 = wsB[(nt0 * 2 + 0) * 64 + lane];
    bf8 bl0 = wsB[(nt0 * 2 + 1) * 64 + lane];
    bf8 bh1 = wsB[((nt0 + 1) * 2 + 0) * 64 + lane];
    bf8 bl1 = wsB[((nt0 + 1) * 2 + 1) * 64 + lane];
    for (int mt = mtb; mt < mte; ++mt) {
      int rr = mt * 16 + r;
      if (rr >= NROWSR) rr = mt * 16 + (r & 7);
      const float* sp = state + ((size_t)b0 * 20 + rr) * 13;
      uint hv[8], lv[8];
#pragma unroll
      for (int e = 0; e < 8; ++e) {
        int k = g * 8 + e;
        float v = (k < 13) ? sp[k] : 0.f;
        uint bits = __builtin_bit_cast(uint, v);
        hv[e] = bits >> 16;
        float hf = __builtin_bit_cast(float, bits & 0xffff0000u);
        lv[e] = __builtin_bit_cast(uint, v - hf) >> 16;
      }
      uint4 H = {hv[0] | (hv[1] << 16), hv[2] | (hv[3] << 16),
                 hv[4] | (hv[5] << 16), hv[6] | (hv[7] << 16)};
      uint4 L = {lv[0] | (lv[1] << 16), lv[2] | (lv[3] << 16),
                 lv[4] | (lv[5] << 16), lv[6] | (lv[7] << 16)};
      bf8 ah = __builtin_bit_cast(bf8, H);
      bf8 al = __builtin_bit_cast(bf8, L);
      f4 acc0 = {0.f, 0.f, 0.f, 0.f}, acc1 = {0.f, 0.f, 0.f, 0.f};
      acc0 = __builtin_amdgcn_mfma_f32_16x16x32_bf16(ah, bh0, acc0, 0, 0, 0);
      acc1 = __builtin_amdgcn_mfma_f32_16x16x32_bf16(ah, bh1, acc1, 0, 0, 0);
      acc0 = __builtin_amdgcn_mfma_f32_16x16x32_bf16(al, bh0, acc0, 0, 0, 0);
      acc1 = __builtin_amdgcn_mfma_f32_16x16x32_bf16(al, bh1, acc1, 0, 0, 0);
      acc0 = __builtin_amdgcn_mfma_f32_16x16x32_bf16(ah, bl0, acc0, 0, 0, 0);
      acc1 = __builtin_amdgcn_mfma_f32_16x16x32_bf16(ah, bl1, acc1, 0, 0, 0);
#pragma unroll
      for (int t = 0; t < 2; ++t) {
        const int nt = nt0 + t;
        const f4 acc = t ? acc1 : acc0;
        const int col = nt * 16 + r;
        const int rbase = mt * 16 + g * 4;
        const float bcol = (col < 150) ? bias[col] : 0.f;
#pragma unroll
        for (int q = 0; q < 4; ++q) {
          const int orow = rbase + q;
          if (orow < NROWSR) {
            float v = (col < 150) ? fmaxf(acc[q] + bcol, 0.f) : 0.f;
            ushort* oHi = (ushort*)(pool + H1_OFF) + orow * H1_PK + col;
            split_store(v, oHi, 40 * H1_PK);
          }
        }
      }
    }
  }
}

// ---------------- kernel1: MLP1 + attention -> joint ----------------
// __launch_bounds__(512,4): VGPR cap 64 (R3-proven spill-free for this loop).
// LDS ~49.5KB -> 3 WGs/CU -> 24 waves/CU.
__global__ __launch_bounds__(NTHR, 4) void value_net_kernel(
    const float* __restrict__ state,
    const float* __restrict__ b1, const float* __restrict__ b2,
    const float* __restrict__ b3,
    const float* __restrict__ a1, const float* __restrict__ ab1,
    const float* __restrict__ ab2,
    const float* __restrict__ a3, const float* __restrict__ ab3,
    const uint4* __restrict__ ws, float* __restrict__ jointg) {
  __shared__ char pool[POOL1];
  __shared__ float gsL[200], gpartL[200], sceL[40], swL[40];

  const int tid = threadIdx.x;
  const int lane = tid & 63, wid = tid >> 6;
  const int b0 = blockIdx.x * NB;
  const bf8* wsb = (const bf8*)ws;

  // P1: L1 13->150 relu (A-frags from state in regs) -> H1
  l1_layer(state, b0, pool, wsb + L1B * 64, b1, lane, wid);
  __syncthreads();

  // P2: zero H2 tail; L2 150->100 relu  H1 -> H2
  zero_tail136<40>(pool, H2_OFF, tid);
  mfma_layer<5, 7, 100, 0, 3, 40, NROWSR, true>(
      pool, H1_OFF, H1_PK, H2_OFF, H2_PK, wsb + L2B * 64, b2,
      nullptr, nullptr, nullptr, lane, wid);
  __syncthreads();

  // P3: zero FEAT tail; L3 100->100 linear  H2 -> FEAT
  zero_tail136<40>(pool, FEAT_OFF, tid);
  mfma_layer<4, 7, 100, 1, 3, 40, NROWSR, true>(
      pool, H2_OFF, H2_PK, FEAT_OFF, FEAT_PK, wsb + L3B * 64, b3,
      nullptr, nullptr, nullptr, lane, wid);
  __syncthreads();

  // P4: gs = mean over n (x0.05)
  if (tid < NB * 100) {
    const int b = tid / 100, d = tid - b * 100;
    const ushort* fh = (const ushort*)(pool + FEAT_OFF);
    const ushort* fl = fh + 40 * FEAT_PK;
    float s = 0.f;
    for (int n = 0; n < 20; ++n) {
      int rw = b * 20 + n;
      s += us2f(fh[rw * FEAT_PK + d]) + us2f(fl[rw * FEAT_PK + d]);
    }
    gsL[b * 100 + d] = s * 0.05f;
  }
  __syncthreads();

  // P5: gpart = gs @ a1[100:200]; zero sceL
  if (tid < 400) {
    const int b = tid / 200, rem = tid - b * 200;
    const int j = rem >> 1, half = rem & 1;
    float acc = 0.f;
    const float* gsb = gsL + b * 100;
    for (int k = half * 50; k < half * 50 + 50; ++k)
      acc += gsb[k] * a1[(100 + k) * 100 + j];
    acc += __shfl_xor(acc, 1);
    if (half == 0) gpartL[b * 100 + j] = acc;
  } else if (tid < 440) {
    sceL[tid - 400] = 0.f;
  }
  __syncthreads();

  // P6: A1 (feat half) + gpart, relu  FEAT -> S1 ([112,128) zeros inherited from H2)
  mfma_layer<4, 7, 100, 2, 3, 40, NROWSR, true>(
      pool, FEAT_OFF, FEAT_PK, S1_OFF, S1_PK, wsb + A1B * 64, ab1,
      gpartL, nullptr, nullptr, lane, wid);
  __syncthreads();

  // P7: A2 relu + A3-dot fold -> sceL atomics (no planar store)
  mfma_layer<4, 7, 100, 3, 3, 40, NROWSR, true>(
      pool, S1_OFF, S1_PK, 0, 0, wsb + A2B * 64, ab2,
      nullptr, sceL, a3, lane, wid);
  __syncthreads();

  // P8: softmax over n of relu(score + ab3)
  if (tid < NROWSR) {
    const int b = tid / 20, n = tid - b * 20;
    const float ab3v = ab3[0];
    float m = -1e30f;
    for (int i = 0; i < 20; ++i) m = fmaxf(m, relu_f(sceL[b * 20 + i] + ab3v));
    float sum = 0.f, mine = 0.f;
    for (int i = 0; i < 20; ++i) {
      float e = __expf(relu_f(sceL[b * 20 + i] + ab3v) - m);
      sum += e;
      if (i == n) mine = e;
    }
    swL[tid] = mine / sum;
  }
  __syncthreads();

  // P9: weighted feature + self -> jointg
  if (tid < 400) {
    const int b = tid / 200, rem = tid - b * 200;
    const int d = rem >> 1, half = rem & 1;
    const ushort* fh = (const ushort*)(pool + FEAT_OFF);
    const ushort* fl = fh + 40 * FEAT_PK;
    float acc = 0.f;
    for (int n = half * 10; n < half * 10 + 10; ++n) {
      const int rw = b * 20 + n;
      acc += swL[b * 20 + n] * (us2f(fh[rw * FEAT_PK + d]) + us2f(fl[rw * FEAT_PK + d]));
    }
    acc += __shfl_xor(acc, 1);
    if (half == 0) jointg[(size_t)(b0 + b) * 106 + 6 + d] = acc;
  } else if (tid < 412) {
    const int idx = tid - 400, b = idx / 6, i = idx - b * 6;
    jointg[(size_t)(b0 + b) * 106 + i] = state[(b0 + b) * 260 + i];
  }
}

// ---------------- kernel2: M-MLP GEMM over 16384 rows (R3-proven) ----------------
__global__ __launch_bounds__(K2THR) void mlp2_kernel(
    const float* __restrict__ jointg,
    const float* __restrict__ mb1, const float* __restrict__ mb2,
    const float* __restrict__ mb3,
    const float* __restrict__ m4, const float* __restrict__ mb4,
    const uint4* __restrict__ ws, float* __restrict__ out) {
  __shared__ char pool[K2_POOL];
  __shared__ float m4L[100];
  const int tid = threadIdx.x, lane = tid & 63, wid = tid >> 6;
  const size_t r0 = (size_t)blockIdx.x * K2ROWS;
  const bf8* wsb = (const bf8*)ws;

  // stage joint -> planar hi/lo (PK=136, cols 106..135 zero); m4 -> LDS
  for (int i = tid; i < K2ROWS * 136; i += K2THR) {
    int row = i / 136, k = i - row * 136;
    float v = (k < 106) ? jointg[(r0 + row) * 106 + k] : 0.f;
    split_store(v, (ushort*)(pool + K2_JT_OFF) + row * 136 + k, K2ROWS * 136);
  }
  if (tid < 100) m4L[tid] = m4[tid];
  __syncthreads();

  // M1: 106->150 relu (jt PK136 -> v1 PK168)
  mfma_layer<4, 10, 150, 0, 4, K2ROWS, K2ROWS, false>(
      pool, K2_JT_OFF, 136, K2_V1_OFF, 168, wsb + M1B * 64, mb1,
      nullptr, nullptr, nullptr, lane, wid);
  __syncthreads();

  // M2: zero v2 tail; 150->100 relu (v1 -> v2 @0 PK136)
  zero_tail136<K2ROWS>(pool, 0, tid);
  mfma_layer<5, 7, 100, 0, 4, K2ROWS, K2ROWS, false>(
      pool, K2_V1_OFF, 168, 0, 136, wsb + M2B * 64, mb2,
      nullptr, nullptr, nullptr, lane, wid);
  __syncthreads();

  // M3: 100->100 relu (v2 -> v3 @V1_OFF PK136)
  mfma_layer<4, 7, 100, 0, 4, K2ROWS, K2ROWS, false>(
      pool, 0, 136, K2_V1_OFF, 136, wsb + M3B * 64, mb3,
      nullptr, nullptr, nullptr, lane, wid);
  __syncthreads();

  // M4: 100->1
  {
    const int row = tid >> 2, seg = tid & 3;
    const ushort* vh = (const ushort*)(pool + K2_V1_OFF);
    const ushort* vl = vh + K2ROWS * 136;
    float s = 0.f;
    for (int k = seg; k < 100; k += 4)
      s += (us2f(vh[row * 136 + k]) + us2f(vl[row * 136 + k])) * m4L[k];
    s += __shfl_xor(s, 1);
    s += __shfl_xor(s, 2);
    if (seg == 0) out[r0 + row] = s + mb4[0];
  }
}

extern "C" void kernel_launch(void* const* d_in, const int* in_sizes, int n_in,
                              void* d_out, int out_size, void* d_ws, size_t ws_size,
                              hipStream_t stream) {
  const float* state = (const float*)d_in[0];
  const float* w1 = (const float*)d_in[1];
  const float* b1 = (const float*)d_in[2];
  const float* w2 = (const float*)d_in[3];
  const float* b2 = (const float*)d_in[4];
  const float* w3 = (const float*)d_in[5];
  const float* b3 = (const float*)d_in[6];
  const float* a1 = (const float*)d_in[7];
  const float* ab1 = (const float*)d_in[8];
  const float* a2 = (const float*)d_in[9];
  const float* ab2 = (const float*)d_in[10];
  const float* a3 = (const float*)d_in[11];
  const float* ab3 = (const float*)d_in[12];
  const float* m1 = (const float*)d_in[13];
  const float* mb1 = (const float*)d_in[14];
  const float* m2 = (const float*)d_in[15];
  const float* mb2 = (const float*)d_in[16];
  const float* m3 = (const float*)d_in[17];
  const float* mb3 = (const float*)d_in[18];
  const float* m4 = (const float*)d_in[19];
  const float* mb4 = (const float*)d_in[20];
  float* out = (float*)d_out;
  uint4* ws = (uint4*)d_ws;
  float* jointg = (float*)d_ws + JOINT_F;

  prep_kernel<<<232, 64, 0, stream>>>(w1, w2, w3, a1, a2, m1, m2, m3, ws);

  const int B = in_sizes[0] / 260;  // 16384
  value_net_kernel<<<dim3(B / NB), dim3(NTHR), 0, stream>>>(
      state, b1, b2, b3, a1, ab1, ab2, a3, ab3, (const uint4*)ws, jointg);

  mlp2_kernel<<<dim3(B / K2ROWS), dim3(K2THR), 0, stream>>>(
      jointg, mb1, mb2, mb3, m4, mb4, (const uint4*)ws, out);
}

// Round 9
// 388.557 us; speedup vs baseline: 2.6937x; 1.0722x over previous
//
#include <hip/hip_runtime.h>
#include <math.h>

#define NTHR 256          // 4 waves; one batch per WG
#define NROWSR 20

using bf8 = __attribute__((ext_vector_type(8))) short;
using f4  = __attribute__((ext_vector_type(4))) float;

// kernel1 LDS pool (bytes). Planar hi/lo bf16: [plane][20][PK].
// Row strides multiple of 16B: PK168->336B, PK136->272B, PK40->80B.
#define H1_OFF 0
#define H1_PK 168        // 20*168*4 = 13440
#define H2_OFF 13440
#define H2_PK 136        // 20*136*4 = 10880 -> end 24320
#define FEAT_OFF 0       // aliases H1 (dead after L2)
#define FEAT_PK 136
#define S1_OFF 13440     // aliases H2 (dead after L3); tail zeros inherited
#define S1_PK 136
#define XS_OFF 13440     // aliases H2 during P0/P1 only (dead after P1)
#define XS_PK 40         // 20*40*4 = 3200
#define POOL1 24320

// ws fragment bases (1KB blocks; each (kb,nt) = 2 blocks hi+lo)
#define L1B 0
#define L2B 20
#define L3B 90
#define A1B 146
#define A2B 202
#define M1B 258
#define M2B 338
#define M3B 408
#define JOINT_F 118784   // float offset of joint[16384][106] in ws

// kernel2 (R3-proven config)
#define K2ROWS 64
#define K2THR 256
#define K2_JT_OFF 0      // 64*136*4 = 34816
#define K2_V1_OFF 34816  // 64*168*4 = 43008 -> end 77824
#define K2_POOL 77824

__device__ __forceinline__ float relu_f(float v) { return fmaxf(v, 0.f); }
__device__ __forceinline__ float us2f(ushort u) {
  return __builtin_bit_cast(float, (uint)u << 16);
}
__device__ __forceinline__ void split_store(float v, ushort* p, int pstride) {
  uint bits = __builtin_bit_cast(uint, v);
  float hf = __builtin_bit_cast(float, bits & 0xffff0000u);
  float lf = v - hf;
  p[0] = (ushort)(bits >> 16);
  p[pstride] = (ushort)(__builtin_bit_cast(uint, lf) >> 16);
}

// ---------------- prep: pack hi/lo bf16 weight B-fragments ----------------
// Frag (kb, nt, plane): lane l holds out-feature j = nt*16 + (l&15),
// k = kb*32 + (l>>4)*8 + e  (16B per lane).
__global__ __launch_bounds__(64) void prep_kernel(
    const float* __restrict__ w1, const float* __restrict__ w2,
    const float* __restrict__ w3, const float* __restrict__ a1,
    const float* __restrict__ a2, const float* __restrict__ m1,
    const float* __restrict__ m2, const float* __restrict__ m3,
    uint4* __restrict__ ws) {
  const int job = blockIdx.x;
  const int lane = threadIdx.x;
  const float* W;
  int K, C, NT, base, kb, nt, i;
  if (job < 10)       { W = w1; K = 13;  C = 150; NT = 10; base = L1B; kb = 0; nt = job; }
  else if (job < 45)  { W = w2; K = 150; C = 100; NT = 7;  base = L2B; i = job - 10;  kb = i / 7;  nt = i % 7; }
  else if (job < 73)  { W = w3; K = 100; C = 100; NT = 7;  base = L3B; i = job - 45;  kb = i / 7;  nt = i % 7; }
  else if (job < 101) { W = a1; K = 100; C = 100; NT = 7;  base = A1B; i = job - 73;  kb = i / 7;  nt = i % 7; }
  else if (job < 129) { W = a2; K = 100; C = 100; NT = 7;  base = A2B; i = job - 101; kb = i / 7;  nt = i % 7; }
  else if (job < 169) { W = m1; K = 106; C = 150; NT = 10; base = M1B; i = job - 129; kb = i / 10; nt = i % 10; }
  else if (job < 204) { W = m2; K = 150; C = 100; NT = 7;  base = M2B; i = job - 169; kb = i / 7;  nt = i % 7; }
  else                { W = m3; K = 100; C = 100; NT = 7;  base = M3B; i = job - 204; kb = i / 7;  nt = i % 7; }
  const int r = lane & 15, g = lane >> 4;
  const int j = nt * 16 + r;
  uint hi[8], lo[8];
  for (int e = 0; e < 8; ++e) {
    int k = kb * 32 + g * 8 + e;
    float v = (k < K && j < C) ? W[k * C + j] : 0.f;
    uint bits = __builtin_bit_cast(uint, v);
    hi[e] = bits >> 16;
    float hf = __builtin_bit_cast(float, bits & 0xffff0000u);
    float lf = v - hf;
    lo[e] = __builtin_bit_cast(uint, lf) >> 16;
  }
  uint4 vh = { hi[0] | (hi[1] << 16), hi[2] | (hi[3] << 16),
               hi[4] | (hi[5] << 16), hi[6] | (hi[7] << 16) };
  uint4 vl = { lo[0] | (lo[1] << 16), lo[2] | (lo[3] << 16),
               lo[4] | (lo[5] << 16), lo[6] | (lo[7] << 16) };
  ws[(size_t)(base + (kb * NT + nt) * 2 + 0) * 64 + lane] = vh;
  ws[(size_t)(base + (kb * NT + nt) * 2 + 1) * 64 + lane] = vl;
}

// ---------------- R3-style MFMA dense layer (act-as-A, weights-as-B) ----------------
// D-layout: col = lane&15 (+nt*16), act row = (lane>>4)*4+q (+mt*16).
// MODE: 0 relu->planar, 1 linear->planar, 2 relu+gpart->planar,
//       3 relu + a3-dot fold -> sceL atomics (no store)
template <int KB, int NT, int C, int MODE, int ROWS, int NWAVES>
__device__ __forceinline__ void mfma_layer(
    char* pool, int inOff, int PKin, int outOff, int PKout,
    const bf8* __restrict__ wsB, const float* __restrict__ bias,
    const float* gpartL, float* sceL, const float* __restrict__ a3,
    int lane, int wid) {
  constexpr int NTP = (NT + 1) / 2;
  constexpr int MTL = (ROWS + 15) / 16;
  constexpr int TAIL = ROWS & 15;   // rows in last tile (0 = full)
  const int r = lane & 15, g = lane >> 4;
  const char* Ain = pool + inOff;
  const int pstr = ROWS * PKin * 2;
  for (int p = wid; p < NTP; p += NWAVES) {
    const int nt0 = 2 * p;
    const bool two = (nt0 + 1 < NT);
    bf8 bh0[KB], bl0[KB], bh1[KB], bl1[KB];
#pragma unroll
    for (int kb = 0; kb < KB; ++kb) {
      bh0[kb] = wsB[((kb * NT + nt0) * 2 + 0) * 64 + lane];
      bl0[kb] = wsB[((kb * NT + nt0) * 2 + 1) * 64 + lane];
      if (two) {
        bh1[kb] = wsB[((kb * NT + nt0 + 1) * 2 + 0) * 64 + lane];
        bl1[kb] = wsB[((kb * NT + nt0 + 1) * 2 + 1) * 64 + lane];
      }
    }
    for (int mt = 0; mt < MTL; ++mt) {
      int rA = mt * 16 + r;
      if constexpr (TAIL != 0) {
        if (mt == MTL - 1 && r >= TAIL) rA = mt * 16 + (r & (TAIL - 1));
      }
      f4 acc0 = {0.f, 0.f, 0.f, 0.f}, acc1 = {0.f, 0.f, 0.f, 0.f};
      const char* aHi = Ain + rA * (PKin * 2) + g * 16;
      const char* aLo = aHi + pstr;
#pragma unroll
      for (int kb = 0; kb < KB; ++kb) {
        bf8 ah = *(const bf8*)(aHi + kb * 64);
        bf8 al = *(const bf8*)(aLo + kb * 64);
        acc0 = __builtin_amdgcn_mfma_f32_16x16x32_bf16(ah, bh0[kb], acc0, 0, 0, 0);
        if (two) acc1 = __builtin_amdgcn_mfma_f32_16x16x32_bf16(ah, bh1[kb], acc1, 0, 0, 0);
        acc0 = __builtin_amdgcn_mfma_f32_16x16x32_bf16(al, bh0[kb], acc0, 0, 0, 0);
        if (two) acc1 = __builtin_amdgcn_mfma_f32_16x16x32_bf16(al, bh1[kb], acc1, 0, 0, 0);
        acc0 = __builtin_amdgcn_mfma_f32_16x16x32_bf16(ah, bl0[kb], acc0, 0, 0, 0);
        if (two) acc1 = __builtin_amdgcn_mfma_f32_16x16x32_bf16(ah, bl1[kb], acc1, 0, 0, 0);
      }
#pragma unroll
      for (int t = 0; t < 2; ++t) {
        if (t && !two) break;
        const int nt = nt0 + t;
        const f4 acc = t ? acc1 : acc0;
        const int col = nt * 16 + r;
        const int rbase = mt * 16 + g * 4;
        const float bcol = (col < C) ? bias[col] : 0.f;
        float gp = 0.f;
        if constexpr (MODE == 2) { if (col < C) gp = gpartL[col]; }
        float a3c = 0.f;
        if constexpr (MODE == 3) { if (col < C) a3c = a3[col]; }
#pragma unroll
        for (int q = 0; q < 4; ++q) {
          const int orow = rbase + q;
          float v = 0.f;
          if (orow < ROWS && col < C) {
            v = acc[q] + bcol;
            if constexpr (MODE == 2) v += gp;
            if constexpr (MODE != 1) v = fmaxf(v, 0.f);
          }
          if constexpr (MODE == 3) {
            float val = v * a3c;
            val += __shfl_xor(val, 1);
            val += __shfl_xor(val, 2);
            val += __shfl_xor(val, 4);
            val += __shfl_xor(val, 8);
            if (r == 0 && orow < ROWS) atomicAdd(&sceL[orow], val);
          } else {
            if (orow < ROWS) {
              ushort* oHi = (ushort*)(pool + outOff) + orow * PKout + col;
              split_store(v, oHi, ROWS * PKout);
            }
          }
        }
      }
    }
  }
}

// zero cols [112,128) of a planar PK=136 buffer (epilogue covers [C,112))
template <int ROWSZ>
__device__ __forceinline__ void zero_tail136(char* pool, int off, int tid) {
  if (tid < 2 * ROWSZ) {
    int row = tid >> 1, pl = tid & 1;
    uint2* z = (uint2*)((ushort*)(pool + off) + (size_t)pl * ROWSZ * 136 + row * 136 + 112);
#pragma unroll
    for (int u = 0; u < 4; ++u) z[u] = uint2{0, 0};
  }
}

// ---------------- kernel1: one batch per 256-thr WG ----------------
// __launch_bounds__(256,8): waves/SIMD cap 8 -> VGPR cap 64 (R3/R8-proven loop).
// LDS ~25.3KB -> 6 blocks/CU -> 24 waves/CU in 6 independent barrier domains.
__global__ __launch_bounds__(NTHR, 8) void value_net_kernel(
    const float* __restrict__ state,
    const float* __restrict__ b1, const float* __restrict__ b2,
    const float* __restrict__ b3,
    const float* __restrict__ a1, const float* __restrict__ ab1,
    const float* __restrict__ ab2,
    const float* __restrict__ a3, const float* __restrict__ ab3,
    const uint4* __restrict__ ws, float* __restrict__ jointg) {
  __shared__ char pool[POOL1];
  __shared__ float gsL[100], gpartL[100], sceL[24], swL[24];

  const int tid = threadIdx.x;
  const int lane = tid & 63, wid = tid >> 6;
  const int b0 = blockIdx.x;       // batch index
  const bf8* wsb = (const bf8*)ws;

  // P0: stage state -> XS planar hi/lo (20 x PK40, cols 13..39 zero); zero sceL
  for (int i = tid; i < 20 * XS_PK; i += NTHR) {
    int row = i / XS_PK, k = i - row * XS_PK;
    float v = (k < 13) ? state[((size_t)b0 * 20 + row) * 13 + k] : 0.f;
    split_store(v, (ushort*)(pool + XS_OFF) + row * XS_PK + k, 20 * XS_PK);
  }
  if (tid < 20) sceL[tid] = 0.f;
  __syncthreads();

  // P1: L1 13->150 relu  XS -> H1 (cols [150,160) zeroed by epilogue)
  mfma_layer<1, 10, 150, 0, NROWSR, 4>(
      pool, XS_OFF, XS_PK, H1_OFF, H1_PK, wsb + L1B * 64, b1,
      nullptr, nullptr, nullptr, lane, wid);
  __syncthreads();

  // P2: zero H2 tail; L2 150->100 relu  H1 -> H2
  zero_tail136<NROWSR>(pool, H2_OFF, tid);
  mfma_layer<5, 7, 100, 0, NROWSR, 4>(
      pool, H1_OFF, H1_PK, H2_OFF, H2_PK, wsb + L2B * 64, b2,
      nullptr, nullptr, nullptr, lane, wid);
  __syncthreads();

  // P3: zero FEAT tail; L3 100->100 linear  H2 -> FEAT
  zero_tail136<NROWSR>(pool, FEAT_OFF, tid);
  mfma_layer<4, 7, 100, 1, NROWSR, 4>(
      pool, H2_OFF, H2_PK, FEAT_OFF, FEAT_PK, wsb + L3B * 64, b3,
      nullptr, nullptr, nullptr, lane, wid);
  __syncthreads();

  // P4: gs = mean over n (x0.05)
  if (tid < 100) {
    const ushort* fh = (const ushort*)(pool + FEAT_OFF);
    const ushort* fl = fh + NROWSR * FEAT_PK;
    float s = 0.f;
    for (int n = 0; n < 20; ++n)
      s += us2f(fh[n * FEAT_PK + tid]) + us2f(fl[n * FEAT_PK + tid]);
    gsL[tid] = s * 0.05f;
  }
  __syncthreads();

  // P5: gpart = gs @ a1[100:200]
  if (tid < 200) {
    const int j = tid >> 1, half = tid & 1;
    float acc = 0.f;
    for (int k = half * 50; k < half * 50 + 50; ++k)
      acc += gsL[k] * a1[(100 + k) * 100 + j];
    acc += __shfl_xor(acc, 1);
    if (half == 0) gpartL[j] = acc;
  }
  __syncthreads();

  // P6: A1 (feat half) + gpart, relu  FEAT -> S1 (tail zeros inherited from H2)
  mfma_layer<4, 7, 100, 2, NROWSR, 4>(
      pool, FEAT_OFF, FEAT_PK, S1_OFF, S1_PK, wsb + A1B * 64, ab1,
      gpartL, nullptr, nullptr, lane, wid);
  __syncthreads();

  // P7: A2 relu + A3-dot fold -> sceL atomics
  mfma_layer<4, 7, 100, 3, NROWSR, 4>(
      pool, S1_OFF, S1_PK, 0, 0, wsb + A2B * 64, ab2,
      nullptr, sceL, a3, lane, wid);
  __syncthreads();

  // P8: softmax over n of relu(score + ab3)
  if (tid < 20) {
    const float ab3v = ab3[0];
    float m = -1e30f;
    for (int i = 0; i < 20; ++i) m = fmaxf(m, relu_f(sceL[i] + ab3v));
    float sum = 0.f, mine = 0.f;
    for (int i = 0; i < 20; ++i) {
      float e = __expf(relu_f(sceL[i] + ab3v) - m);
      sum += e;
      if (i == tid) mine = e;
    }
    swL[tid] = mine / sum;
  }
  __syncthreads();

  // P9: weighted feature + self -> jointg
  if (tid < 200) {
    const int d = tid >> 1, half = tid & 1;
    const ushort* fh = (const ushort*)(pool + FEAT_OFF);
    const ushort* fl = fh + NROWSR * FEAT_PK;
    float acc = 0.f;
    for (int n = half * 10; n < half * 10 + 10; ++n)
      acc += swL[n] * (us2f(fh[n * FEAT_PK + d]) + us2f(fl[n * FEAT_PK + d]));
    acc += __shfl_xor(acc, 1);
    if (half == 0) jointg[(size_t)b0 * 106 + 6 + d] = acc;
  } else if (tid < 206) {
    const int i = tid - 200;
    jointg[(size_t)b0 * 106 + i] = state[(size_t)b0 * 260 + i];
  }
}

// ---------------- kernel2: M-MLP GEMM over 16384 rows (R3-proven) ----------------
__global__ __launch_bounds__(K2THR) void mlp2_kernel(
    const float* __restrict__ jointg,
    const float* __restrict__ mb1, const float* __restrict__ mb2,
    const float* __restrict__ mb3,
    const float* __restrict__ m4, const float* __restrict__ mb4,
    const uint4* __restrict__ ws, float* __restrict__ out) {
  __shared__ char pool[K2_POOL];
  __shared__ float m4L[100];
  const int tid = threadIdx.x, lane = tid & 63, wid = tid >> 6;
  const size_t r0 = (size_t)blockIdx.x * K2ROWS;
  const bf8* wsb = (const bf8*)ws;

  // stage joint -> planar hi/lo (PK=136, cols 106..135 zero); m4 -> LDS
  for (int i = tid; i < K2ROWS * 136; i += K2THR) {
    int row = i / 136, k = i - row * 136;
    float v = (k < 106) ? jointg[(r0 + row) * 106 + k] : 0.f;
    split_store(v, (ushort*)(pool + K2_JT_OFF) + row * 136 + k, K2ROWS * 136);
  }
  if (tid < 100) m4L[tid] = m4[tid];
  __syncthreads();

  // M1: 106->150 relu (jt PK136 -> v1 PK168)
  mfma_layer<4, 10, 150, 0, K2ROWS, 4>(
      pool, K2_JT_OFF, 136, K2_V1_OFF, 168, wsb + M1B * 64, mb1,
      nullptr, nullptr, nullptr, lane, wid);
  __syncthreads();

  // M2: zero v2 tail; 150->100 relu (v1 -> v2 @0 PK136)
  zero_tail136<K2ROWS>(pool, 0, tid);
  mfma_layer<5, 7, 100, 0, K2ROWS, 4>(
      pool, K2_V1_OFF, 168, 0, 136, wsb + M2B * 64, mb2,
      nullptr, nullptr, nullptr, lane, wid);
  __syncthreads();

  // M3: 100->100 relu (v2 -> v3 @V1_OFF PK136)
  mfma_layer<4, 7, 100, 0, K2ROWS, 4>(
      pool, 0, 136, K2_V1_OFF, 136, wsb + M3B * 64, mb3,
      nullptr, nullptr, nullptr, lane, wid);
  __syncthreads();

  // M4: 100->1
  {
    const int row = tid >> 2, seg = tid & 3;
    const ushort* vh = (const ushort*)(pool + K2_V1_OFF);
    const ushort* vl = vh + K2ROWS * 136;
    float s = 0.f;
    for (int k = seg; k < 100; k += 4)
      s += (us2f(vh[row * 136 + k]) + us2f(vl[row * 136 + k])) * m4L[k];
    s += __shfl_xor(s, 1);
    s += __shfl_xor(s, 2);
    if (seg == 0) out[r0 + row] = s + mb4[0];
  }
}

extern "C" void kernel_launch(void* const* d_in, const int* in_sizes, int n_in,
                              void* d_out, int out_size, void* d_ws, size_t ws_size,
                              hipStream_t stream) {
  const float* state = (const float*)d_in[0];
  const float* w1 = (const float*)d_in[1];
  const float* b1 = (const float*)d_in[2];
  const float* w2 = (const float*)d_in[3];
  const float* b2 = (const float*)d_in[4];
  const float* w3 = (const float*)d_in[5];
  const float* b3 = (const float*)d_in[6];
  const float* a1 = (const float*)d_in[7];
  const float* ab1 = (const float*)d_in[8];
  const float* a2 = (const float*)d_in[9];
  const float* ab2 = (const float*)d_in[10];
  const float* a3 = (const float*)d_in[11];
  const float* ab3 = (const float*)d_in[12];
  const float* m1 = (const float*)d_in[13];
  const float* mb1 = (const float*)d_in[14];
  const float* m2 = (const float*)d_in[15];
  const float* mb2 = (const float*)d_in[16];
  const float* m3 = (const float*)d_in[17];
  const float* mb3 = (const float*)d_in[18];
  const float* m4 = (const float*)d_in[19];
  const float* mb4 = (const float*)d_in[20];
  float* out = (float*)d_out;
  uint4* ws = (uint4*)d_ws;
  float* jointg = (float*)d_ws + JOINT_F;

  prep_kernel<<<232, 64, 0, stream>>>(w1, w2, w3, a1, a2, m1, m2, m3, ws);

  const int B = in_sizes[0] / 260;  // 16384
  value_net_kernel<<<dim3(B), dim3(NTHR), 0, stream>>>(
      state, b1, b2, b3, a1, ab1, ab2, a3, ab3, (const uint4*)ws, jointg);

  mlp2_kernel<<<dim3(B / K2ROWS), dim3(K2THR), 0, stream>>>(
      jointg, mb1, mb2, mb3, m4, mb4, (const uint4*)ws, out);
}